// Round 7
// baseline (837.319 us; speedup 1.0000x reference)
//
#include <hip/hip_runtime.h>
#include <hip/hip_bf16.h>
#include <math.h>

#define NB 32
#define NT 2048
#define NC 1024
#define NM 131072
#define TOPK 8
#define TCH 32              // t-chunks for mean
#define MBLK 128            // m rows per score block
#define SBLOCKS (NM / MBLK) // 1024

// ws layout (float offsets). candS/candI OVERLAY part (part is dead after
// mean_finalize_k; scores_topk_k runs after qproj_k on the same stream).
#define OFF_PART 0
#define OFF_CS   0
#define OFF_CI   262144
#define OFF_MEAN 1048576
#define OFF_Q    (OFF_MEAN + 32768)

__global__ __launch_bounds__(256) void mean_partial_k(const float* __restrict__ seg,
                                                      float* __restrict__ part) {
    int blk = blockIdx.x;            // 1024 = 32 b * 32 tc
    int b = blk >> 5, tc = blk & 31;
    int tid = threadIdx.x;
    const float4* src = (const float4*)(seg + ((size_t)b * NT + (size_t)tc * 64) * NC);
    float4 acc = make_float4(0.f, 0.f, 0.f, 0.f);
#pragma unroll 4
    for (int t = 0; t < 64; ++t) {
        float4 v = src[(size_t)t * 256 + tid];
        acc.x += v.x; acc.y += v.y; acc.z += v.z; acc.w += v.w;
    }
    ((float4*)(part + ((size_t)b * 32 + tc) * NC))[tid] = acc;
}

__global__ __launch_bounds__(256) void mean_finalize_k(const float* __restrict__ part,
                                                       float* __restrict__ mean) {
    int i = blockIdx.x * 256 + threadIdx.x;   // 32768
    int b = i >> 10, c = i & 1023;
    float s = 0.f;
#pragma unroll
    for (int tc = 0; tc < 32; ++tc) s += part[((size_t)b * 32 + tc) * NC + c];
    mean[i] = s * (1.0f / NT);
}

__global__ __launch_bounds__(256) void qproj_k(const float* __restrict__ mean,
                                               const float* __restrict__ Wq,
                                               const float* __restrict__ bq,
                                               float* __restrict__ q) {
    int wave = (blockIdx.x * 256 + threadIdx.x) >> 6;   // 2048 waves
    int lane = threadIdx.x & 63;
    int o0 = wave * 16;
    for (int j = 0; j < 16; ++j) {
        int o = o0 + j;                 // < 32768
        int b = o >> 10, i = o & 1023;
        const float4* wr = (const float4*)(Wq + (size_t)i * NC);
        const float4* mr = (const float4*)(mean + (size_t)b * NC);
        float acc = 0.f;
#pragma unroll
        for (int e = 0; e < 4; ++e) {
            float4 w4 = wr[lane * 4 + e];
            float4 m4 = mr[lane * 4 + e];
            acc += w4.x * m4.x + w4.y * m4.y + w4.z * m4.z + w4.w * m4.w;
        }
#pragma unroll
        for (int off = 32; off; off >>= 1) acc += __shfl_xor(acc, off);
        if (lane == 0) q[o] = acc + bq[i];
    }
}

// branchless top-8 insert, all-static indexing (keeps s/si in VGPRs)
#define BUBBLE8(v, vi, s, si)                                   \
    {                                                           \
        float _v = (v); int _vi = (vi);                         \
        _Pragma("unroll")                                       \
        for (int _u = 0; _u < 8; ++_u) {                        \
            bool _gt = _v > s[_u];                              \
            float _ts = _gt ? _v : s[_u];                       \
            int _ti = _gt ? _vi : si[_u];                       \
            _v = _gt ? s[_u] : _v;                              \
            _vi = _gt ? si[_u] : _vi;                           \
            s[_u] = _ts; si[_u] = _ti;                          \
        }                                                       \
    }

// Scores: block = 128 m x 32 b. 4 waves = (mhalf, bhalf); lanes mgrp16 x cgrp4.
// Thread: acc[4 m][16 b] over its c-quad slice.
// q: FULL chunk double-buffer in registers (qA/qB, 16 float4 each), loaded one
//   chunk ahead -> L2 latency hidden under 512 cyc of FMA. (256,2) cap=256 VGPR
//   so the ~230-reg set fits with no spill and no compiler load-sinking.
// x-tile: staging c4s=tid&3, rs=tid>>2 -> 16 rows x 64B per instr (16 lines);
//   XOR-swizzled [c4][r^c4] layout -> conflict-free ds_write and ds_read.
__global__ __launch_bounds__(256, 2) void scores_topk_k(const float* __restrict__ memb,
                                                        const float* __restrict__ q,
                                                        float* __restrict__ candS,
                                                        int* __restrict__ candI) {
    __shared__ __align__(16) float smemf[5760];   // 23 KB: tile dbuf 4096f | score/tree reuse
    float4* smem = (float4*)smemf;                // [2][512] float4 tile buffers
    int tid = threadIdx.x, lane = tid & 63, wid = tid >> 6;
    int mhalf = wid & 1, bhalf = wid >> 1;
    int mgrp = lane & 15, cgrp = lane >> 4;
    int m0 = blockIdx.x * MBLK;
    int c4s = tid & 3, rs = tid >> 2;             // staging: c-quad, row

    float acc[4][16];
#pragma unroll
    for (int mr = 0; mr < 4; ++mr)
#pragma unroll
        for (int bb = 0; bb < 16; ++bb) acc[mr][bb] = 0.f;

    const float* gbase = memb + (size_t)(m0 + rs) * NC + c4s * 4;
    const float* qbase = q + (size_t)(bhalf * 16) * NC + cgrp * 4;
    int sw0 = c4s * 128 + (rs ^ c4s);             // +64 for row rs+64 (bit6 untouched by xor)

    float4 rt0, rt1, qA[16], qB[16];

#define STAGE_LOAD(cc_) { const float* g2 = gbase + (cc_) * 16;                       \
    rt0 = *(const float4*)(g2); rt1 = *(const float4*)(g2 + (size_t)64 * NC); }
#define QLOAD(dst, cc_) { _Pragma("unroll")                                           \
    for (int bb = 0; bb < 16; ++bb)                                                   \
        dst[bb] = *(const float4*)(qbase + (size_t)bb * NC + (cc_) * 16); }
#define LDSW(buf_) { float4* tb = smem + (buf_) * 512; tb[sw0] = rt0; tb[sw0 + 64] = rt1; }
#define COMPUTE(buf_, qq) { const float4* tb = smem + (buf_) * 512; float4 x[4];      \
    _Pragma("unroll") for (int mr = 0; mr < 4; ++mr)                                  \
        x[mr] = tb[cgrp * 128 + ((mhalf * 64 + mgrp + 16 * mr) ^ cgrp)];              \
    _Pragma("unroll") for (int bb = 0; bb < 16; ++bb)                                 \
        _Pragma("unroll") for (int mr = 0; mr < 4; ++mr)                              \
            acc[mr][bb] = fmaf(x[mr].x, qq[bb].x, fmaf(x[mr].y, qq[bb].y,             \
                          fmaf(x[mr].z, qq[bb].z, fmaf(x[mr].w, qq[bb].w,             \
                          acc[mr][bb])))); }

    // prologue: stage chunk 0, q for chunk 0
    STAGE_LOAD(0);
    QLOAD(qA, 0);
    LDSW(0);
    __syncthreads();

    for (int cc = 0; cc < 64; cc += 2) {
        STAGE_LOAD(cc + 1);          // issue next-chunk loads before compute
        QLOAD(qB, cc + 1);
        COMPUTE(0, qA);
        LDSW(1);
        __syncthreads();
        if (cc + 2 < 64) { STAGE_LOAD(cc + 2); QLOAD(qA, cc + 2); }
        COMPUTE(1, qB);
        if (cc + 2 < 64) LDSW(0);
        __syncthreads();
    }
#undef STAGE_LOAD
#undef QLOAD
#undef LDSW
#undef COMPUTE

    // reduce over 4 cgrp lanes; write scores [32 b][128 m]
    float* fb = smemf;   // 4096 floats
#pragma unroll
    for (int mr = 0; mr < 4; ++mr)
#pragma unroll
        for (int bb = 0; bb < 16; ++bb) {
            float v = acc[mr][bb];
            v += __shfl_xor(v, 16);
            v += __shfl_xor(v, 32);
            if (cgrp == (bb & 3))
                fb[(bhalf * 16 + bb) * MBLK + mhalf * 64 + mgrp + 16 * mr] = v * 0.03125f;
        }
    __syncthreads();

    // per-b top-8: 8 threads per b, each scans 16 scores (rotated -> <=2-way banks)
    {
        int b = tid >> 3, p = tid & 7;
        float s[8]; int si[8];
#pragma unroll
        for (int u = 0; u < 8; ++u) { s[u] = -INFINITY; si[u] = -1; }
#pragma unroll
        for (int j = 0; j < 16; ++j) {
            int ml = (p + j * 8 + b * 4) & 127;
            float v = fb[b * MBLK + ml];
            BUBBLE8(v, m0 + ml, s, si);
        }
        __syncthreads();   // scores consumed; reuse LDS for candidate tree (stride 9)
        float* cs = smemf;                    // [256][9] floats at [0,2304)
        int* ci = (int*)(smemf + 2304);       // [256][9] ints  at [2304,4608)
#pragma unroll
        for (int u = 0; u < 8; ++u) { cs[tid * 9 + u] = s[u]; ci[tid * 9 + u] = si[u]; }
        __syncthreads();
        float* csA = smemf + 4608;            // [64][9]
        int* ciA = (int*)(smemf + 5184);      // [64][9] -> ends 5760
        if (tid < 64) {
            float s2[8]; int si2[8];
#pragma unroll
            for (int u = 0; u < 8; ++u) { s2[u] = -INFINITY; si2[u] = -1; }
            int t0 = (tid >> 1) * 8 + (tid & 1) * 4;
            for (int tt = 0; tt < 4; ++tt)
#pragma unroll
                for (int u = 0; u < 8; ++u)
                    BUBBLE8(cs[(t0 + tt) * 9 + u], ci[(t0 + tt) * 9 + u], s2, si2);
#pragma unroll
            for (int u = 0; u < 8; ++u) { csA[tid * 9 + u] = s2[u]; ciA[tid * 9 + u] = si2[u]; }
        }
        __syncthreads();
        if (tid < 32) {
            float s3[8]; int si3[8];
#pragma unroll
            for (int u = 0; u < 8; ++u) { s3[u] = -INFINITY; si3[u] = -1; }
            for (int j = 0; j < 16; ++j)
                BUBBLE8(csA[(tid * 2 + (j >> 3)) * 9 + (j & 7)],
                        ciA[(tid * 2 + (j >> 3)) * 9 + (j & 7)], s3, si3);
#pragma unroll
            for (int u = 0; u < 8; ++u) {
                candS[((size_t)tid * SBLOCKS + blockIdx.x) * 8 + u] = s3[u];
                candI[((size_t)tid * SBLOCKS + blockIdx.x) * 8 + u] = si3[u];
            }
        }
    }
}

__global__ __launch_bounds__(256) void finalize_k(const float* __restrict__ candS,
                                                  const int* __restrict__ candI,
                                                  const float* __restrict__ memb,
                                                  float* __restrict__ out) {
    __shared__ float cs[2048 + 256 + 32 + 8];
    __shared__ int ci[2048 + 256 + 32 + 8];
    int b = blockIdx.x, tid = threadIdx.x;
    const float* S = candS + (size_t)b * (SBLOCKS * 8);
    const int* I = candI + (size_t)b * (SBLOCKS * 8);
    float s[8]; int si[8];
#pragma unroll
    for (int u = 0; u < 8; ++u) { s[u] = -INFINITY; si[u] = -1; }
    for (int j = 0; j < 32; ++j)
        BUBBLE8(S[tid * 32 + j], I[tid * 32 + j], s, si);
#pragma unroll
    for (int u = 0; u < 8; ++u) { cs[tid * 8 + u] = s[u]; ci[tid * 8 + u] = si[u]; }
    __syncthreads();
    if (tid < 32) {
        float s2[8]; int si2[8];
#pragma unroll
        for (int u = 0; u < 8; ++u) { s2[u] = -INFINITY; si2[u] = -1; }
        for (int j = 0; j < 64; ++j)
            BUBBLE8(cs[tid * 64 + j], ci[tid * 64 + j], s2, si2);
#pragma unroll
        for (int u = 0; u < 8; ++u) { cs[2048 + tid * 8 + u] = s2[u]; ci[2048 + tid * 8 + u] = si2[u]; }
    }
    __syncthreads();
    if (tid < 4) {
        float s3[8]; int si3[8];
#pragma unroll
        for (int u = 0; u < 8; ++u) { s3[u] = -INFINITY; si3[u] = -1; }
        for (int j = 0; j < 64; ++j)
            BUBBLE8(cs[2048 + tid * 64 + j], ci[2048 + tid * 64 + j], s3, si3);
#pragma unroll
        for (int u = 0; u < 8; ++u) { cs[2304 + tid * 8 + u] = s3[u]; ci[2304 + tid * 8 + u] = si3[u]; }
    }
    __syncthreads();
    if (tid == 0) {
        float s4[8]; int si4[8];
#pragma unroll
        for (int u = 0; u < 8; ++u) { s4[u] = -INFINITY; si4[u] = -1; }
        for (int j = 0; j < 32; ++j)
            BUBBLE8(cs[2304 + j], ci[2304 + j], s4, si4);
        // softmax over sorted-desc top-8 (s4[0] is max)
        float m = s4[0], sum = 0.f;
        float w[8];
#pragma unroll
        for (int u = 0; u < 8; ++u) { w[u] = __expf(s4[u] - m); sum += w[u]; }
        float inv = 1.0f / sum;
#pragma unroll
        for (int u = 0; u < 8; ++u) { cs[2336 + u] = w[u] * inv; ci[2336 + u] = si4[u]; }
    }
    __syncthreads();
    float wv[8]; int ix[8];
#pragma unroll
    for (int u = 0; u < 8; ++u) { wv[u] = cs[2336 + u]; ix[u] = ci[2336 + u]; }
    float4 o = make_float4(0.f, 0.f, 0.f, 0.f);
#pragma unroll
    for (int u = 0; u < 8; ++u) {
        float4 r = ((const float4*)(memb + (size_t)ix[u] * NC))[tid];
        o.x = fmaf(wv[u], r.x, o.x);
        o.y = fmaf(wv[u], r.y, o.y);
        o.z = fmaf(wv[u], r.z, o.z);
        o.w = fmaf(wv[u], r.w, o.w);
    }
    ((float4*)(out + (size_t)b * NC))[tid] = o;
}

extern "C" void kernel_launch(void* const* d_in, const int* in_sizes, int n_in,
                              void* d_out, int out_size, void* d_ws, size_t ws_size,
                              hipStream_t stream) {
    const float* seg  = (const float*)d_in[0];
    const float* Wq   = (const float*)d_in[1];
    const float* bq   = (const float*)d_in[2];
    const float* memb = (const float*)d_in[3];
    float* ws = (float*)d_ws;
    float* part  = ws + OFF_PART;
    float* mean  = ws + OFF_MEAN;
    float* q     = ws + OFF_Q;
    float* candS = ws + OFF_CS;           // overlays part (safe: part dead by then)
    int*   candI = (int*)(ws + OFF_CI);
    float* out = (float*)d_out;

    mean_partial_k<<<NB * TCH, 256, 0, stream>>>(seg, part);
    mean_finalize_k<<<(NB * NC) / 256, 256, 0, stream>>>(part, mean);
    qproj_k<<<512, 256, 0, stream>>>(mean, Wq, bq, q);
    scores_topk_k<<<SBLOCKS, 256, 0, stream>>>(memb, q, candS, candI);
    finalize_k<<<NB, 256, 0, stream>>>(candS, candI, memb, out);
}

// Round 8
// 359.687 us; speedup vs baseline: 2.3279x; 2.3279x over previous
//
#include <hip/hip_runtime.h>
#include <hip/hip_bf16.h>
#include <math.h>

#define NB 32
#define NT 2048
#define NC 1024
#define NM 131072
#define TOPK 8
#define TCH 32              // t-chunks for mean
#define MBLK 128            // m rows per score block
#define SBLOCKS (NM / MBLK) // 1024

// ws layout (float offsets). candS/candI OVERLAY part (part is dead after
// mean_finalize_k; scores_topk_k runs after qproj_k on the same stream).
#define OFF_PART 0
#define OFF_CS   0
#define OFF_CI   262144
#define OFF_MEAN 1048576
#define OFF_Q    (OFF_MEAN + 32768)

__global__ __launch_bounds__(256) void mean_partial_k(const float* __restrict__ seg,
                                                      float* __restrict__ part) {
    int blk = blockIdx.x;            // 1024 = 32 b * 32 tc
    int b = blk >> 5, tc = blk & 31;
    int tid = threadIdx.x;
    const float4* src = (const float4*)(seg + ((size_t)b * NT + (size_t)tc * 64) * NC);
    float4 acc = make_float4(0.f, 0.f, 0.f, 0.f);
#pragma unroll 4
    for (int t = 0; t < 64; ++t) {
        float4 v = src[(size_t)t * 256 + tid];
        acc.x += v.x; acc.y += v.y; acc.z += v.z; acc.w += v.w;
    }
    ((float4*)(part + ((size_t)b * 32 + tc) * NC))[tid] = acc;
}

__global__ __launch_bounds__(256) void mean_finalize_k(const float* __restrict__ part,
                                                       float* __restrict__ mean) {
    int i = blockIdx.x * 256 + threadIdx.x;   // 32768
    int b = i >> 10, c = i & 1023;
    float s = 0.f;
#pragma unroll
    for (int tc = 0; tc < 32; ++tc) s += part[((size_t)b * 32 + tc) * NC + c];
    mean[i] = s * (1.0f / NT);
}

__global__ __launch_bounds__(256) void qproj_k(const float* __restrict__ mean,
                                               const float* __restrict__ Wq,
                                               const float* __restrict__ bq,
                                               float* __restrict__ q) {
    int wave = (blockIdx.x * 256 + threadIdx.x) >> 6;   // 2048 waves
    int lane = threadIdx.x & 63;
    int o0 = wave * 16;
    for (int j = 0; j < 16; ++j) {
        int o = o0 + j;                 // < 32768
        int b = o >> 10, i = o & 1023;
        const float4* wr = (const float4*)(Wq + (size_t)i * NC);
        const float4* mr = (const float4*)(mean + (size_t)b * NC);
        float acc = 0.f;
#pragma unroll
        for (int e = 0; e < 4; ++e) {
            float4 w4 = wr[lane * 4 + e];
            float4 m4 = mr[lane * 4 + e];
            acc += w4.x * m4.x + w4.y * m4.y + w4.z * m4.z + w4.w * m4.w;
        }
#pragma unroll
        for (int off = 32; off; off >>= 1) acc += __shfl_xor(acc, off);
        if (lane == 0) q[o] = acc + bq[i];
    }
}

// branchless top-8 insert, all-static indexing (keeps s/si in VGPRs)
#define BUBBLE8(v, vi, s, si)                                   \
    {                                                           \
        float _v = (v); int _vi = (vi);                         \
        _Pragma("unroll")                                       \
        for (int _u = 0; _u < 8; ++_u) {                        \
            bool _gt = _v > s[_u];                              \
            float _ts = _gt ? _v : s[_u];                       \
            int _ti = _gt ? _vi : si[_u];                       \
            _v = _gt ? s[_u] : _v;                              \
            _vi = _gt ? si[_u] : _vi;                           \
            s[_u] = _ts; si[_u] = _ti;                          \
        }                                                       \
    }

// Scores: block = 128 m x 32 b. 4 waves = (mhalf, bhalf); lanes mgrp16 x cgrp4.
// Thread: acc[4 m][16 b] over its c-quad slice.
// q: PHASE-level double buffer qcA/qcB (4 float4 each, +16 VGPR only) — each
//   phase issues next phase's 4 loads, then sched_barrier(0) pins them before
//   the 64-FMA block so the allocator cannot sink them (R7 lesson).
// x-tile: staging c4s=tid&3, rs=tid>>2 (16 lines/instr); XOR-swizzled
//   [c4][r^c4] -> uniform bank spread on ds_write and ds_read; 16 KB dbuf.
__global__ __launch_bounds__(256, 3) void scores_topk_k(const float* __restrict__ memb,
                                                        const float* __restrict__ q,
                                                        float* __restrict__ candS,
                                                        int* __restrict__ candI) {
    __shared__ __align__(16) float smemf[5760];   // 23 KB: tile dbuf 4096f | score/tree reuse
    float4* smem = (float4*)smemf;                // [2][512] float4 tile buffers
    int tid = threadIdx.x, lane = tid & 63, wid = tid >> 6;
    int mhalf = wid & 1, bhalf = wid >> 1;
    int mgrp = lane & 15, cgrp = lane >> 4;
    int m0 = blockIdx.x * MBLK;
    int c4s = tid & 3, rs = tid >> 2;             // staging: c-quad, row

    float acc[4][16];
#pragma unroll
    for (int mr = 0; mr < 4; ++mr)
#pragma unroll
        for (int bb = 0; bb < 16; ++bb) acc[mr][bb] = 0.f;

    const float* gbase = memb + (size_t)(m0 + rs) * NC + c4s * 4;
    const float* qbase = q + (size_t)(bhalf * 16) * NC + cgrp * 4;
    int sw0 = c4s * 128 + (rs ^ c4s);             // row rs; +64 for rs+64 (bit6 safe)

    float4 rt0, rt1, qcA[4], qcB[4];

#define STAGE_LOAD(cc_) { const float* g2 = gbase + (cc_) * 16;                       \
    rt0 = *(const float4*)(g2); rt1 = *(const float4*)(g2 + (size_t)64 * NC); }
#define QLOAD(dst, cc_, h_) { _Pragma("unroll")                                       \
    for (int bb = 0; bb < 4; ++bb)                                                    \
        dst[bb] = *(const float4*)(qbase + (size_t)((h_) * 4 + bb) * NC + (cc_) * 16); }
#define LDSW(buf_) { float4* tb = smem + (buf_) * 512; tb[sw0] = rt0; tb[sw0 + 64] = rt1; }
#define CPHASE(qq, h_) { _Pragma("unroll") for (int bb = 0; bb < 4; ++bb)             \
    _Pragma("unroll") for (int mr = 0; mr < 4; ++mr)                                  \
        acc[mr][(h_) * 4 + bb] = fmaf(x[mr].x, qq[bb].x, fmaf(x[mr].y, qq[bb].y,      \
                                 fmaf(x[mr].z, qq[bb].z, fmaf(x[mr].w, qq[bb].w,      \
                                 acc[mr][(h_) * 4 + bb])))); }

    // prologue: stage chunk 0; q phase 0
    STAGE_LOAD(0);
    QLOAD(qcA, 0, 0);
    LDSW(0);
    __syncthreads();

    for (int cc = 0; cc < 64; ++cc) {
        int cur = cc & 1;
        if (cc < 63) STAGE_LOAD(cc + 1);          // next tile chunk -> regs (HBM latency
                                                  // covered by this whole chunk's compute)
        const float4* tb = smem + cur * 512;
        float4 x[4];
#pragma unroll
        for (int mr = 0; mr < 4; ++mr)
            x[mr] = tb[cgrp * 128 + ((mhalf * 64 + mgrp + 16 * mr) ^ cgrp)];

        QLOAD(qcB, cc, 1);                        // prefetch phase 1
        __builtin_amdgcn_sched_barrier(0);
        CPHASE(qcA, 0);
        QLOAD(qcA, cc, 2);                        // prefetch phase 2
        __builtin_amdgcn_sched_barrier(0);
        CPHASE(qcB, 1);
        QLOAD(qcB, cc, 3);                        // prefetch phase 3
        __builtin_amdgcn_sched_barrier(0);
        CPHASE(qcA, 2);
        if (cc < 63) QLOAD(qcA, cc + 1, 0);       // prefetch next chunk phase 0
        __builtin_amdgcn_sched_barrier(0);
        CPHASE(qcB, 3);

        if (cc < 63) LDSW(cur ^ 1);
        __syncthreads();
    }
#undef STAGE_LOAD
#undef QLOAD
#undef LDSW
#undef CPHASE

    // reduce over 4 cgrp lanes; write scores [32 b][128 m]
    float* fb = smemf;   // 4096 floats
#pragma unroll
    for (int mr = 0; mr < 4; ++mr)
#pragma unroll
        for (int bb = 0; bb < 16; ++bb) {
            float v = acc[mr][bb];
            v += __shfl_xor(v, 16);
            v += __shfl_xor(v, 32);
            if (cgrp == (bb & 3))
                fb[(bhalf * 16 + bb) * MBLK + mhalf * 64 + mgrp + 16 * mr] = v * 0.03125f;
        }
    __syncthreads();

    // per-b top-8: 8 threads per b, each scans 16 scores (rotated -> <=2-way banks)
    {
        int b = tid >> 3, p = tid & 7;
        float s[8]; int si[8];
#pragma unroll
        for (int u = 0; u < 8; ++u) { s[u] = -INFINITY; si[u] = -1; }
#pragma unroll
        for (int j = 0; j < 16; ++j) {
            int ml = (p + j * 8 + b * 4) & 127;
            float v = fb[b * MBLK + ml];
            BUBBLE8(v, m0 + ml, s, si);
        }
        __syncthreads();   // scores consumed; reuse LDS for candidate tree (stride 9)
        float* cs = smemf;                    // [256][9] floats at [0,2304)
        int* ci = (int*)(smemf + 2304);       // [256][9] ints  at [2304,4608)
#pragma unroll
        for (int u = 0; u < 8; ++u) { cs[tid * 9 + u] = s[u]; ci[tid * 9 + u] = si[u]; }
        __syncthreads();
        float* csA = smemf + 4608;            // [64][9]
        int* ciA = (int*)(smemf + 5184);      // [64][9] -> ends 5760
        if (tid < 64) {
            float s2[8]; int si2[8];
#pragma unroll
            for (int u = 0; u < 8; ++u) { s2[u] = -INFINITY; si2[u] = -1; }
            int t0 = (tid >> 1) * 8 + (tid & 1) * 4;
            for (int tt = 0; tt < 4; ++tt)
#pragma unroll
                for (int u = 0; u < 8; ++u)
                    BUBBLE8(cs[(t0 + tt) * 9 + u], ci[(t0 + tt) * 9 + u], s2, si2);
#pragma unroll
            for (int u = 0; u < 8; ++u) { csA[tid * 9 + u] = s2[u]; ciA[tid * 9 + u] = si2[u]; }
        }
        __syncthreads();
        if (tid < 32) {
            float s3[8]; int si3[8];
#pragma unroll
            for (int u = 0; u < 8; ++u) { s3[u] = -INFINITY; si3[u] = -1; }
            for (int j = 0; j < 16; ++j)
                BUBBLE8(csA[(tid * 2 + (j >> 3)) * 9 + (j & 7)],
                        ciA[(tid * 2 + (j >> 3)) * 9 + (j & 7)], s3, si3);
#pragma unroll
            for (int u = 0; u < 8; ++u) {
                candS[((size_t)tid * SBLOCKS + blockIdx.x) * 8 + u] = s3[u];
                candI[((size_t)tid * SBLOCKS + blockIdx.x) * 8 + u] = si3[u];
            }
        }
    }
}

__global__ __launch_bounds__(256) void finalize_k(const float* __restrict__ candS,
                                                  const int* __restrict__ candI,
                                                  const float* __restrict__ memb,
                                                  float* __restrict__ out) {
    __shared__ float cs[2048 + 256 + 32 + 8];
    __shared__ int ci[2048 + 256 + 32 + 8];
    int b = blockIdx.x, tid = threadIdx.x;
    const float* S = candS + (size_t)b * (SBLOCKS * 8);
    const int* I = candI + (size_t)b * (SBLOCKS * 8);
    float s[8]; int si[8];
#pragma unroll
    for (int u = 0; u < 8; ++u) { s[u] = -INFINITY; si[u] = -1; }
    for (int j = 0; j < 32; ++j)
        BUBBLE8(S[tid * 32 + j], I[tid * 32 + j], s, si);
#pragma unroll
    for (int u = 0; u < 8; ++u) { cs[tid * 8 + u] = s[u]; ci[tid * 8 + u] = si[u]; }
    __syncthreads();
    if (tid < 32) {
        float s2[8]; int si2[8];
#pragma unroll
        for (int u = 0; u < 8; ++u) { s2[u] = -INFINITY; si2[u] = -1; }
        for (int j = 0; j < 64; ++j)
            BUBBLE8(cs[tid * 64 + j], ci[tid * 64 + j], s2, si2);
#pragma unroll
        for (int u = 0; u < 8; ++u) { cs[2048 + tid * 8 + u] = s2[u]; ci[2048 + tid * 8 + u] = si2[u]; }
    }
    __syncthreads();
    if (tid < 4) {
        float s3[8]; int si3[8];
#pragma unroll
        for (int u = 0; u < 8; ++u) { s3[u] = -INFINITY; si3[u] = -1; }
        for (int j = 0; j < 64; ++j)
            BUBBLE8(cs[2048 + tid * 64 + j], ci[2048 + tid * 64 + j], s3, si3);
#pragma unroll
        for (int u = 0; u < 8; ++u) { cs[2304 + tid * 8 + u] = s3[u]; ci[2304 + tid * 8 + u] = si3[u]; }
    }
    __syncthreads();
    if (tid == 0) {
        float s4[8]; int si4[8];
#pragma unroll
        for (int u = 0; u < 8; ++u) { s4[u] = -INFINITY; si4[u] = -1; }
        for (int j = 0; j < 32; ++j)
            BUBBLE8(cs[2304 + j], ci[2304 + j], s4, si4);
        // softmax over sorted-desc top-8 (s4[0] is max)
        float m = s4[0], sum = 0.f;
        float w[8];
#pragma unroll
        for (int u = 0; u < 8; ++u) { w[u] = __expf(s4[u] - m); sum += w[u]; }
        float inv = 1.0f / sum;
#pragma unroll
        for (int u = 0; u < 8; ++u) { cs[2336 + u] = w[u] * inv; ci[2336 + u] = si4[u]; }
    }
    __syncthreads();
    float wv[8]; int ix[8];
#pragma unroll
    for (int u = 0; u < 8; ++u) { wv[u] = cs[2336 + u]; ix[u] = ci[2336 + u]; }
    float4 o = make_float4(0.f, 0.f, 0.f, 0.f);
#pragma unroll
    for (int u = 0; u < 8; ++u) {
        float4 r = ((const float4*)(memb + (size_t)ix[u] * NC))[tid];
        o.x = fmaf(wv[u], r.x, o.x);
        o.y = fmaf(wv[u], r.y, o.y);
        o.z = fmaf(wv[u], r.z, o.z);
        o.w = fmaf(wv[u], r.w, o.w);
    }
    ((float4*)(out + (size_t)b * NC))[tid] = o;
}

extern "C" void kernel_launch(void* const* d_in, const int* in_sizes, int n_in,
                              void* d_out, int out_size, void* d_ws, size_t ws_size,
                              hipStream_t stream) {
    const float* seg  = (const float*)d_in[0];
    const float* Wq   = (const float*)d_in[1];
    const float* bq   = (const float*)d_in[2];
    const float* memb = (const float*)d_in[3];
    float* ws = (float*)d_ws;
    float* part  = ws + OFF_PART;
    float* mean  = ws + OFF_MEAN;
    float* q     = ws + OFF_Q;
    float* candS = ws + OFF_CS;           // overlays part (safe: part dead by then)
    int*   candI = (int*)(ws + OFF_CI);
    float* out = (float*)d_out;

    mean_partial_k<<<NB * TCH, 256, 0, stream>>>(seg, part);
    mean_finalize_k<<<(NB * NC) / 256, 256, 0, stream>>>(part, mean);
    qproj_k<<<512, 256, 0, stream>>>(mean, Wq, bq, q);
    scores_topk_k<<<SBLOCKS, 256, 0, stream>>>(memb, q, candS, candI);
    finalize_k<<<NB, 256, 0, stream>>>(candS, candI, memb, out);
}

// Round 10
// 262.156 us; speedup vs baseline: 3.1940x; 1.3720x over previous
//
#include <hip/hip_runtime.h>
#include <hip/hip_bf16.h>
#include <math.h>

#define NB 32
#define NT 2048
#define NC 1024
#define NM 131072
#define TOPK 8
#define MBLK 256            // m rows per score block
#define SBLOCKS (NM / MBLK) // 512

typedef __attribute__((ext_vector_type(8))) short s16x8;   // 8 bf16 (4 VGPR)
typedef __attribute__((ext_vector_type(4))) float f32x4;   // MFMA acc

// ws layout (float offsets). candS/candI OVERLAY part (part dead after mean_finalize_k).
#define OFF_PART 0
#define OFF_CS   0
#define OFF_CI   262144
#define OFF_MEAN 1048576
#define OFF_Q    (OFF_MEAN + 32768)
#define OFF_QB   (OFF_Q + 32768)     // 4096 s16x8 = 64 KB = 16384 floats

__device__ __forceinline__ unsigned short f2bf(float f) {
    // RNE f32 -> bf16 (finite inputs)
    unsigned u = __float_as_uint(f);
    unsigned r = (u + 0x7FFFu + ((u >> 16) & 1u)) >> 16;
    return (unsigned short)r;
}

__global__ __launch_bounds__(256) void mean_partial_k(const float* __restrict__ seg,
                                                      float* __restrict__ part) {
    int blk = blockIdx.x;            // 1024 = 32 b * 32 tc
    int b = blk >> 5, tc = blk & 31;
    int tid = threadIdx.x;
    const float4* src = (const float4*)(seg + ((size_t)b * NT + (size_t)tc * 64) * NC);
    float4 acc = make_float4(0.f, 0.f, 0.f, 0.f);
#pragma unroll 4
    for (int t = 0; t < 64; ++t) {
        float4 v = src[(size_t)t * 256 + tid];
        acc.x += v.x; acc.y += v.y; acc.z += v.z; acc.w += v.w;
    }
    ((float4*)(part + ((size_t)b * 32 + tc) * NC))[tid] = acc;
}

__global__ __launch_bounds__(256) void mean_finalize_k(const float* __restrict__ part,
                                                       float* __restrict__ mean) {
    int i = blockIdx.x * 256 + threadIdx.x;   // 32768
    int b = i >> 10, c = i & 1023;
    float s = 0.f;
#pragma unroll
    for (int tc = 0; tc < 32; ++tc) s += part[((size_t)b * 32 + tc) * NC + c];
    mean[i] = s * (1.0f / NT);
}

__global__ __launch_bounds__(256) void qproj_k(const float* __restrict__ mean,
                                               const float* __restrict__ Wq,
                                               const float* __restrict__ bq,
                                               float* __restrict__ q) {
    int wave = (blockIdx.x * 256 + threadIdx.x) >> 6;   // 2048 waves
    int lane = threadIdx.x & 63;
    int o0 = wave * 16;
    for (int j = 0; j < 16; ++j) {
        int o = o0 + j;                 // < 32768
        int b = o >> 10, i = o & 1023;
        const float4* wr = (const float4*)(Wq + (size_t)i * NC);
        const float4* mr = (const float4*)(mean + (size_t)b * NC);
        float acc = 0.f;
#pragma unroll
        for (int e = 0; e < 4; ++e) {
            float4 w4 = wr[lane * 4 + e];
            float4 m4 = mr[lane * 4 + e];
            acc += w4.x * m4.x + w4.y * m4.y + w4.z * m4.z + w4.w * m4.w;
        }
#pragma unroll
        for (int off = 32; off; off >>= 1) acc += __shfl_xor(acc, off);
        if (lane == 0) q[o] = acc + bq[i];
    }
}

// Build B-fragments: qb[(ks*2+n)*64 + lane][e] = bf16(q[n*16+(lane&15)][ks*32+(lane>>4)*8+e])
__global__ __launch_bounds__(256) void qbf_k(const float* __restrict__ q,
                                             s16x8* __restrict__ qb) {
    int idx = blockIdx.x * 256 + threadIdx.x;   // 4096
    int lane = idx & 63, n = (idx >> 6) & 1, ks = idx >> 7;
    int b = n * 16 + (lane & 15);
    int k0 = ks * 32 + ((lane >> 4) << 3);
    s16x8 v;
#pragma unroll
    for (int e = 0; e < 8; ++e) v[e] = (short)f2bf(q[(size_t)b * NC + k0 + e]);
    qb[idx] = v;
}

// branchless top-8 insert, all-static indexing (keeps s/si in VGPRs)
#define BUBBLE8(v, vi, s, si)                                   \
    {                                                           \
        float _v = (v); int _vi = (vi);                         \
        _Pragma("unroll")                                       \
        for (int _u = 0; _u < 8; ++_u) {                        \
            bool _gt = _v > s[_u];                              \
            float _ts = _gt ? _v : s[_u];                       \
            int _ti = _gt ? _vi : si[_u];                       \
            _v = _gt ? s[_u] : _v;                              \
            _vi = _gt ? si[_u] : _vi;                           \
            s[_u] = _ts; si[_u] = _ti;                          \
        }                                                       \
    }

// bf16 MFMA approx scores + per-block top-8/b filter. Block = 256 m x 32 b,
// 4 waves (64 rows each = 4 M-tiles of 16). No LDS in K-loop: A fragments load
// directly global->reg->bf16 (lane&15 = row, lane>>4 = k-octet); B fragments
// from precomputed qb (L2-hot, 64 KB). 8 MFMA per wave-K-step; pure HBM stream.
__global__ __launch_bounds__(256) void scores_mfma_k(const float* __restrict__ memb,
                                                     const s16x8* __restrict__ qb,
                                                     float* __restrict__ candS,
                                                     int* __restrict__ candI) {
    __shared__ __align__(16) float smemf[32 * 257];   // 32,896 B (scores, then tree overlay)
    int tid = threadIdx.x, lane = tid & 63, wid = tid >> 6;
    int m0 = blockIdx.x * MBLK;

    f32x4 acc[4][2];
#pragma unroll
    for (int t = 0; t < 4; ++t)
#pragma unroll
        for (int n = 0; n < 2; ++n)
            acc[t][n] = (f32x4){0.f, 0.f, 0.f, 0.f};

    const float* abase = memb + (size_t)(m0 + wid * 64 + (lane & 15)) * NC + ((lane >> 4) << 3);
    for (int ks = 0; ks < 32; ++ks) {
        s16x8 bf0 = qb[(ks * 2 + 0) * 64 + lane];
        s16x8 bf1 = qb[(ks * 2 + 1) * 64 + lane];
#pragma unroll
        for (int t = 0; t < 4; ++t) {
            const float* ap = abase + (size_t)(t * 16) * NC + ks * 32;
            float4 lo = *(const float4*)(ap);
            float4 hi = *(const float4*)(ap + 4);
            s16x8 a;
            a[0] = (short)f2bf(lo.x); a[1] = (short)f2bf(lo.y);
            a[2] = (short)f2bf(lo.z); a[3] = (short)f2bf(lo.w);
            a[4] = (short)f2bf(hi.x); a[5] = (short)f2bf(hi.y);
            a[6] = (short)f2bf(hi.z); a[7] = (short)f2bf(hi.w);
            acc[t][0] = __builtin_amdgcn_mfma_f32_16x16x32_bf16(a, bf0, acc[t][0], 0, 0, 0);
            acc[t][1] = __builtin_amdgcn_mfma_f32_16x16x32_bf16(a, bf1, acc[t][1], 0, 0, 0);
        }
    }

    // D layout (m89-verified): col = lane&15 (b within n-tile), row = (lane>>4)*4+j
#pragma unroll
    for (int t = 0; t < 4; ++t)
#pragma unroll
        for (int n = 0; n < 2; ++n)
#pragma unroll
            for (int j = 0; j < 4; ++j) {
                int bb = n * 16 + (lane & 15);
                int mm = wid * 64 + t * 16 + ((lane >> 4) << 2) + j;
                smemf[bb * 257 + mm] = acc[t][n][j] * 0.03125f;
            }
    __syncthreads();

    // per-b top-8 (approx): 8 threads per b, each scans 32 of 256 scores
    {
        int b = tid >> 3, p = tid & 7;
        float s[8]; int si[8];
#pragma unroll
        for (int u = 0; u < 8; ++u) { s[u] = -INFINITY; si[u] = -1; }
        for (int j = 0; j < 32; ++j) {
            int ml = (p + j * 8 + b * 4) & 255;
            float v = smemf[b * 257 + ml];
            BUBBLE8(v, m0 + ml, s, si);
        }
        __syncthreads();   // scores consumed; overlay candidate tree (stride 9)
        float* cs = smemf;                    // [256][9] at [0,2304)
        int* ci = (int*)(smemf + 2304);       // [256][9] at [2304,4608)
#pragma unroll
        for (int u = 0; u < 8; ++u) { cs[tid * 9 + u] = s[u]; ci[tid * 9 + u] = si[u]; }
        __syncthreads();
        float* csA = smemf + 4608;            // [64][9]
        int* ciA = (int*)(smemf + 5184);      // [64][9] -> ends 5760 (< 8224)
        if (tid < 64) {
            float s2[8]; int si2[8];
#pragma unroll
            for (int u = 0; u < 8; ++u) { s2[u] = -INFINITY; si2[u] = -1; }
            int t0 = (tid >> 1) * 8 + (tid & 1) * 4;
            for (int tt = 0; tt < 4; ++tt)
#pragma unroll
                for (int u = 0; u < 8; ++u)
                    BUBBLE8(cs[(t0 + tt) * 9 + u], ci[(t0 + tt) * 9 + u], s2, si2);
#pragma unroll
            for (int u = 0; u < 8; ++u) { csA[tid * 9 + u] = s2[u]; ciA[tid * 9 + u] = si2[u]; }
        }
        __syncthreads();
        if (tid < 32) {
            float s3[8]; int si3[8];
#pragma unroll
            for (int u = 0; u < 8; ++u) { s3[u] = -INFINITY; si3[u] = -1; }
            for (int j = 0; j < 16; ++j)
                BUBBLE8(csA[(tid * 2 + (j >> 3)) * 9 + (j & 7)],
                        ciA[(tid * 2 + (j >> 3)) * 9 + (j & 7)], s3, si3);
#pragma unroll
            for (int u = 0; u < 8; ++u) {
                candS[((size_t)tid * SBLOCKS + blockIdx.x) * 8 + u] = s3[u];
                candI[((size_t)tid * SBLOCKS + blockIdx.x) * 8 + u] = si3[u];
            }
        }
    }
}

// Per b: merge 4096 approx candidates -> 64 survivors -> EXACT f32 rescore ->
// exact top-8 + softmax + weighted gather.
__global__ __launch_bounds__(256) void finalize_k(const float* __restrict__ candS,
                                                  const int* __restrict__ candI,
                                                  const float* __restrict__ memb,
                                                  const float* __restrict__ q,
                                                  float* __restrict__ out) {
    __shared__ float cs[256 * 9];
    __shared__ int ci[256 * 9];
    __shared__ float csA[64 * 9];
    __shared__ int ciA[64 * 9];
    __shared__ float exsc[64];
    __shared__ int exid[64];
    __shared__ float wgt[8];
    __shared__ int widx[8];
    int b = blockIdx.x, tid = threadIdx.x;
    const float* S = candS + (size_t)b * (SBLOCKS * 8);
    const int* I = candI + (size_t)b * (SBLOCKS * 8);

    {   // A: 256 threads x 16 candidates
        float s[8]; int si[8];
#pragma unroll
        for (int u = 0; u < 8; ++u) { s[u] = -INFINITY; si[u] = -1; }
        for (int j = 0; j < 16; ++j)
            BUBBLE8(S[tid * 16 + j], I[tid * 16 + j], s, si);
#pragma unroll
        for (int u = 0; u < 8; ++u) { cs[tid * 9 + u] = s[u]; ci[tid * 9 + u] = si[u]; }
    }
    __syncthreads();
    if (tid < 64) {   // B: merge 4 lists
        float s[8]; int si[8];
#pragma unroll
        for (int u = 0; u < 8; ++u) { s[u] = -INFINITY; si[u] = -1; }
        for (int tt = 0; tt < 4; ++tt)
#pragma unroll
            for (int u = 0; u < 8; ++u)
                BUBBLE8(cs[(tid * 4 + tt) * 9 + u], ci[(tid * 4 + tt) * 9 + u], s, si);
#pragma unroll
        for (int u = 0; u < 8; ++u) { csA[tid * 9 + u] = s[u]; ciA[tid * 9 + u] = si[u]; }
    }
    __syncthreads();
    if (tid < 8) {    // C: merge 8 lists -> 8 survivors each (64 total, superset of true top-8)
        float s[8]; int si[8];
#pragma unroll
        for (int u = 0; u < 8; ++u) { s[u] = -INFINITY; si[u] = -1; }
        for (int tt = 0; tt < 8; ++tt)
#pragma unroll
            for (int u = 0; u < 8; ++u)
                BUBBLE8(csA[(tid * 8 + tt) * 9 + u], ciA[(tid * 8 + tt) * 9 + u], s, si);
#pragma unroll
        for (int u = 0; u < 8; ++u) exid[tid * 8 + u] = si[u];
    }
    __syncthreads();
    {   // D: exact f32 rescore of 64 survivors; wave w -> candidates w*16..+15
        int w = tid >> 6, lane = tid & 63;
        const float4* qr = (const float4*)(q + (size_t)b * NC);   // FIX: per-batch q
        for (int i = 0; i < 16; ++i) {
            int c = w * 16 + i;
            int row = exid[c];
            const float4* mr = (const float4*)(memb + (size_t)row * NC);
            float d = 0.f;
#pragma unroll
            for (int e = 0; e < 4; ++e) {
                float4 m4 = mr[e * 64 + lane];
                float4 q4 = qr[e * 64 + lane];
                d += m4.x * q4.x + m4.y * q4.y + m4.z * q4.z + m4.w * q4.w;
            }
#pragma unroll
            for (int off = 32; off; off >>= 1) d += __shfl_xor(d, off);
            if (lane == 0) exsc[c] = d * 0.03125f;
        }
    }
    __syncthreads();
    if (tid == 0) {   // E: exact top-8 of 64 + softmax
        float s4[8]; int si4[8];
#pragma unroll
        for (int u = 0; u < 8; ++u) { s4[u] = -INFINITY; si4[u] = -1; }
        for (int j = 0; j < 64; ++j)
            BUBBLE8(exsc[j], exid[j], s4, si4);
        float m = s4[0], sum = 0.f, w[8];
#pragma unroll
        for (int u = 0; u < 8; ++u) { w[u] = __expf(s4[u] - m); sum += w[u]; }
        float inv = 1.0f / sum;
#pragma unroll
        for (int u = 0; u < 8; ++u) { wgt[u] = w[u] * inv; widx[u] = si4[u]; }
    }
    __syncthreads();
    {   // F: weighted gather
        float wv[8]; int ix[8];
#pragma unroll
        for (int u = 0; u < 8; ++u) { wv[u] = wgt[u]; ix[u] = widx[u]; }
        float4 o = make_float4(0.f, 0.f, 0.f, 0.f);
#pragma unroll
        for (int u = 0; u < 8; ++u) {
            float4 r = ((const float4*)(memb + (size_t)ix[u] * NC))[tid];
            o.x = fmaf(wv[u], r.x, o.x);
            o.y = fmaf(wv[u], r.y, o.y);
            o.z = fmaf(wv[u], r.z, o.z);
            o.w = fmaf(wv[u], r.w, o.w);
        }
        ((float4*)(out + (size_t)b * NC))[tid] = o;
    }
}

extern "C" void kernel_launch(void* const* d_in, const int* in_sizes, int n_in,
                              void* d_out, int out_size, void* d_ws, size_t ws_size,
                              hipStream_t stream) {
    const float* seg  = (const float*)d_in[0];
    const float* Wq   = (const float*)d_in[1];
    const float* bq   = (const float*)d_in[2];
    const float* memb = (const float*)d_in[3];
    float* ws = (float*)d_ws;
    float* part  = ws + OFF_PART;
    float* mean  = ws + OFF_MEAN;
    float* q     = ws + OFF_Q;
    s16x8* qb    = (s16x8*)(ws + OFF_QB);
    float* candS = ws + OFF_CS;           // overlays part (safe: part dead by then)
    int*   candI = (int*)(ws + OFF_CI);
    float* out = (float*)d_out;

    mean_partial_k<<<NB * 32, 256, 0, stream>>>(seg, part);
    mean_finalize_k<<<(NB * NC) / 256, 256, 0, stream>>>(part, mean);
    qproj_k<<<512, 256, 0, stream>>>(mean, Wq, bq, q);
    qbf_k<<<16, 256, 0, stream>>>(q, qb);
    scores_mfma_k<<<SBLOCKS, 256, 0, stream>>>(memb, qb, candS, candI);
    finalize_k<<<NB, 256, 0, stream>>>(candS, candI, memb, q, out);
}

// Round 11
// 233.840 us; speedup vs baseline: 3.5807x; 1.1211x over previous
//
#include <hip/hip_runtime.h>
#include <hip/hip_bf16.h>
#include <math.h>

#define NB 32
#define NT 2048
#define NC 1024
#define NM 131072
#define TOPK 8
#define MBLK 128            // m rows per score block
#define SBLOCKS (NM / MBLK) // 1024

typedef __attribute__((ext_vector_type(8))) short s16x8;   // 8 bf16 (4 VGPR)
typedef __attribute__((ext_vector_type(4))) float f32x4;   // MFMA acc
typedef __attribute__((ext_vector_type(4))) int i32x4;

// ws layout (float offsets). candS/candI OVERLAY part (part dead after mean_finalize_k).
#define OFF_PART 0
#define OFF_CS   0
#define OFF_CI   262144
#define OFF_MEAN 1048576
#define OFF_Q    (OFF_MEAN + 32768)
#define OFF_QB   (OFF_Q + 32768)     // 4096 s16x8 = 64 KB

__device__ __forceinline__ unsigned short f2bf(float f) {
    // RNE f32 -> bf16 (finite inputs) — used only in qbf precompute
    unsigned u = __float_as_uint(f);
    unsigned r = (u + 0x7FFFu + ((u >> 16) & 1u)) >> 16;
    return (unsigned short)r;
}

__global__ __launch_bounds__(256) void mean_partial_k(const float* __restrict__ seg,
                                                      float* __restrict__ part) {
    int blk = blockIdx.x;            // 1024 = 32 b * 32 tc
    int b = blk >> 5, tc = blk & 31;
    int tid = threadIdx.x;
    const float4* src = (const float4*)(seg + ((size_t)b * NT + (size_t)tc * 64) * NC);
    float4 acc = make_float4(0.f, 0.f, 0.f, 0.f);
#pragma unroll 4
    for (int t = 0; t < 64; ++t) {
        float4 v = src[(size_t)t * 256 + tid];
        acc.x += v.x; acc.y += v.y; acc.z += v.z; acc.w += v.w;
    }
    ((float4*)(part + ((size_t)b * 32 + tc) * NC))[tid] = acc;
}

__global__ __launch_bounds__(256) void mean_finalize_k(const float* __restrict__ part,
                                                       float* __restrict__ mean) {
    int i = blockIdx.x * 256 + threadIdx.x;   // 32768
    int b = i >> 10, c = i & 1023;
    float s = 0.f;
#pragma unroll
    for (int tc = 0; tc < 32; ++tc) s += part[((size_t)b * 32 + tc) * NC + c];
    mean[i] = s * (1.0f / NT);
}

__global__ __launch_bounds__(256) void qproj_k(const float* __restrict__ mean,
                                               const float* __restrict__ Wq,
                                               const float* __restrict__ bq,
                                               float* __restrict__ q) {
    int wave = (blockIdx.x * 256 + threadIdx.x) >> 6;   // 2048 waves
    int lane = threadIdx.x & 63;
    int o0 = wave * 16;
    for (int j = 0; j < 16; ++j) {
        int o = o0 + j;                 // < 32768
        int b = o >> 10, i = o & 1023;
        const float4* wr = (const float4*)(Wq + (size_t)i * NC);
        const float4* mr = (const float4*)(mean + (size_t)b * NC);
        float acc = 0.f;
#pragma unroll
        for (int e = 0; e < 4; ++e) {
            float4 w4 = wr[lane * 4 + e];
            float4 m4 = mr[lane * 4 + e];
            acc += w4.x * m4.x + w4.y * m4.y + w4.z * m4.z + w4.w * m4.w;
        }
#pragma unroll
        for (int off = 32; off; off >>= 1) acc += __shfl_xor(acc, off);
        if (lane == 0) q[o] = acc + bq[i];
    }
}

// Build B-fragments: qb[(ks*2+n)*64 + lane][e] = bf16(q[n*16+(lane&15)][ks*32+(lane>>4)*8+e])
__global__ __launch_bounds__(256) void qbf_k(const float* __restrict__ q,
                                             s16x8* __restrict__ qb) {
    int idx = blockIdx.x * 256 + threadIdx.x;   // 4096
    int lane = idx & 63, n = (idx >> 6) & 1, ks = idx >> 7;
    int b = n * 16 + (lane & 15);
    int k0 = ks * 32 + ((lane >> 4) << 3);
    s16x8 v;
#pragma unroll
    for (int e = 0; e < 8; ++e) v[e] = (short)f2bf(q[(size_t)b * NC + k0 + e]);
    qb[idx] = v;
}

// branchless top-8 insert, all-static indexing (keeps s/si in VGPRs)
#define BUBBLE8(v, vi, s, si)                                   \
    {                                                           \
        float _v = (v); int _vi = (vi);                         \
        _Pragma("unroll")                                       \
        for (int _u = 0; _u < 8; ++_u) {                        \
            bool _gt = _v > s[_u];                              \
            float _ts = _gt ? _v : s[_u];                       \
            int _ti = _gt ? _vi : si[_u];                       \
            _v = _gt ? s[_u] : _v;                              \
            _vi = _gt ? si[_u] : _vi;                           \
            s[_u] = _ts; si[_u] = _ti;                          \
        }                                                       \
    }

// bf16 MFMA approx scores + per-block top-8/b filter. Block = 128 m x 32 b,
// 4 waves (32 rows each = 2 M-tiles of 16). grid 1024 -> 4 blocks/CU, 16 waves/CU.
// A: global->reg, TRUNCATED to bf16 via v_perm (1 op per 2 elems; filter-grade).
// B: precomputed qb (L2-hot), register-prefetched one ks ahead. Pure HBM stream.
__global__ __launch_bounds__(256) void scores_mfma_k(const float* __restrict__ memb,
                                                     const s16x8* __restrict__ qb,
                                                     float* __restrict__ candS,
                                                     int* __restrict__ candI) {
    __shared__ __align__(16) float smemf[5760];   // 23 KB: scores [32][129] then tree overlay
    int tid = threadIdx.x, lane = tid & 63, wid = tid >> 6;
    int m0 = blockIdx.x * MBLK;

    f32x4 acc[2][2];
#pragma unroll
    for (int t = 0; t < 2; ++t)
#pragma unroll
        for (int n = 0; n < 2; ++n)
            acc[t][n] = (f32x4){0.f, 0.f, 0.f, 0.f};

    const unsigned* abase = (const unsigned*)(memb
        + (size_t)(m0 + wid * 32 + (lane & 15)) * NC + ((lane >> 4) << 3));
    s16x8 bf0 = qb[0 * 64 + lane];
    s16x8 bf1 = qb[1 * 64 + lane];

    for (int ks = 0; ks < 32; ++ks) {
        s16x8 nb0, nb1;
        if (ks < 31) {
            nb0 = qb[((ks + 1) * 2 + 0) * 64 + lane];
            nb1 = qb[((ks + 1) * 2 + 1) * 64 + lane];
        }
#pragma unroll
        for (int t = 0; t < 2; ++t) {
            const unsigned* ap = abase + (size_t)(t * 16) * NC + ks * 32;
            uint4 lo = *(const uint4*)(ap);
            uint4 hi = *(const uint4*)(ap + 4);
            i32x4 ai;
            ai[0] = __builtin_amdgcn_perm(lo.y, lo.x, 0x07060302u);  // bf(x)|bf(y)<<16
            ai[1] = __builtin_amdgcn_perm(lo.w, lo.z, 0x07060302u);
            ai[2] = __builtin_amdgcn_perm(hi.y, hi.x, 0x07060302u);
            ai[3] = __builtin_amdgcn_perm(hi.w, hi.z, 0x07060302u);
            s16x8 a = __builtin_bit_cast(s16x8, ai);
            acc[t][0] = __builtin_amdgcn_mfma_f32_16x16x32_bf16(a, bf0, acc[t][0], 0, 0, 0);
            acc[t][1] = __builtin_amdgcn_mfma_f32_16x16x32_bf16(a, bf1, acc[t][1], 0, 0, 0);
        }
        bf0 = nb0; bf1 = nb1;
    }

    // D layout (m89-verified): col = lane&15 (b within n-tile), row = (lane>>4)*4+j
#pragma unroll
    for (int t = 0; t < 2; ++t)
#pragma unroll
        for (int n = 0; n < 2; ++n)
#pragma unroll
            for (int j = 0; j < 4; ++j) {
                int bb = n * 16 + (lane & 15);
                int mm = wid * 32 + t * 16 + ((lane >> 4) << 2) + j;
                smemf[bb * 129 + mm] = acc[t][n][j] * 0.03125f;
            }
    __syncthreads();

    // per-b top-8 (approx): 8 threads per b, each scans 16 of 128 scores
    {
        int b = tid >> 3, p = tid & 7;
        float s[8]; int si[8];
#pragma unroll
        for (int u = 0; u < 8; ++u) { s[u] = -INFINITY; si[u] = -1; }
#pragma unroll
        for (int j = 0; j < 16; ++j) {
            int ml = (p + j * 8 + b * 4) & 127;
            float v = smemf[b * 129 + ml];
            BUBBLE8(v, m0 + ml, s, si);
        }
        __syncthreads();   // scores consumed; overlay candidate tree (stride 9)
        float* cs = smemf;                    // [256][9] at [0,2304)
        int* ci = (int*)(smemf + 2304);       // [256][9] at [2304,4608)
#pragma unroll
        for (int u = 0; u < 8; ++u) { cs[tid * 9 + u] = s[u]; ci[tid * 9 + u] = si[u]; }
        __syncthreads();
        float* csA = smemf + 4608;            // [64][9]
        int* ciA = (int*)(smemf + 5184);      // [64][9] -> ends 5760
        if (tid < 64) {
            float s2[8]; int si2[8];
#pragma unroll
            for (int u = 0; u < 8; ++u) { s2[u] = -INFINITY; si2[u] = -1; }
            int t0 = (tid >> 1) * 8 + (tid & 1) * 4;
            for (int tt = 0; tt < 4; ++tt)
#pragma unroll
                for (int u = 0; u < 8; ++u)
                    BUBBLE8(cs[(t0 + tt) * 9 + u], ci[(t0 + tt) * 9 + u], s2, si2);
#pragma unroll
            for (int u = 0; u < 8; ++u) { csA[tid * 9 + u] = s2[u]; ciA[tid * 9 + u] = si2[u]; }
        }
        __syncthreads();
        if (tid < 32) {
            float s3[8]; int si3[8];
#pragma unroll
            for (int u = 0; u < 8; ++u) { s3[u] = -INFINITY; si3[u] = -1; }
            for (int j = 0; j < 16; ++j)
                BUBBLE8(csA[(tid * 2 + (j >> 3)) * 9 + (j & 7)],
                        ciA[(tid * 2 + (j >> 3)) * 9 + (j & 7)], s3, si3);
#pragma unroll
            for (int u = 0; u < 8; ++u) {
                candS[((size_t)tid * SBLOCKS + blockIdx.x) * 8 + u] = s3[u];
                candI[((size_t)tid * SBLOCKS + blockIdx.x) * 8 + u] = si3[u];
            }
        }
    }
}

// Per b: merge 8192 approx candidates -> 64 survivors -> EXACT f32 rescore ->
// exact top-8 + softmax + weighted gather.
__global__ __launch_bounds__(256) void finalize_k(const float* __restrict__ candS,
                                                  const int* __restrict__ candI,
                                                  const float* __restrict__ memb,
                                                  const float* __restrict__ q,
                                                  float* __restrict__ out) {
    __shared__ float cs[256 * 9];
    __shared__ int ci[256 * 9];
    __shared__ float csA[64 * 9];
    __shared__ int ciA[64 * 9];
    __shared__ float exsc[64];
    __shared__ int exid[64];
    __shared__ float wgt[8];
    __shared__ int widx[8];
    int b = blockIdx.x, tid = threadIdx.x;
    const float* S = candS + (size_t)b * (SBLOCKS * 8);
    const int* I = candI + (size_t)b * (SBLOCKS * 8);

    {   // A: 256 threads x 32 candidates
        float s[8]; int si[8];
#pragma unroll
        for (int u = 0; u < 8; ++u) { s[u] = -INFINITY; si[u] = -1; }
        for (int j = 0; j < 32; ++j)
            BUBBLE8(S[tid * 32 + j], I[tid * 32 + j], s, si);
#pragma unroll
        for (int u = 0; u < 8; ++u) { cs[tid * 9 + u] = s[u]; ci[tid * 9 + u] = si[u]; }
    }
    __syncthreads();
    if (tid < 64) {   // B: merge 4 lists
        float s[8]; int si[8];
#pragma unroll
        for (int u = 0; u < 8; ++u) { s[u] = -INFINITY; si[u] = -1; }
        for (int tt = 0; tt < 4; ++tt)
#pragma unroll
            for (int u = 0; u < 8; ++u)
                BUBBLE8(cs[(tid * 4 + tt) * 9 + u], ci[(tid * 4 + tt) * 9 + u], s, si);
#pragma unroll
        for (int u = 0; u < 8; ++u) { csA[tid * 9 + u] = s[u]; ciA[tid * 9 + u] = si[u]; }
    }
    __syncthreads();
    if (tid < 8) {    // C: merge 8 lists -> 8 survivors each (64 total, superset of true top-8)
        float s[8]; int si[8];
#pragma unroll
        for (int u = 0; u < 8; ++u) { s[u] = -INFINITY; si[u] = -1; }
        for (int tt = 0; tt < 8; ++tt)
#pragma unroll
            for (int u = 0; u < 8; ++u)
                BUBBLE8(csA[(tid * 8 + tt) * 9 + u], ciA[(tid * 8 + tt) * 9 + u], s, si);
#pragma unroll
        for (int u = 0; u < 8; ++u) exid[tid * 8 + u] = si[u];
    }
    __syncthreads();
    {   // D: exact f32 rescore of 64 survivors; wave w -> candidates w*16..+15
        int w = tid >> 6, lane = tid & 63;
        const float4* qr = (const float4*)(q + (size_t)b * NC);
        for (int i = 0; i < 16; ++i) {
            int c = w * 16 + i;
            int row = exid[c];
            const float4* mr = (const float4*)(memb + (size_t)row * NC);
            float d = 0.f;
#pragma unroll
            for (int e = 0; e < 4; ++e) {
                float4 m4 = mr[e * 64 + lane];
                float4 q4 = qr[e * 64 + lane];
                d += m4.x * q4.x + m4.y * q4.y + m4.z * q4.z + m4.w * q4.w;
            }
#pragma unroll
            for (int off = 32; off; off >>= 1) d += __shfl_xor(d, off);
            if (lane == 0) exsc[c] = d * 0.03125f;
        }
    }
    __syncthreads();
    if (tid == 0) {   // E: exact top-8 of 64 + softmax
        float s4[8]; int si4[8];
#pragma unroll
        for (int u = 0; u < 8; ++u) { s4[u] = -INFINITY; si4[u] = -1; }
        for (int j = 0; j < 64; ++j)
            BUBBLE8(exsc[j], exid[j], s4, si4);
        float m = s4[0], sum = 0.f, w[8];
#pragma unroll
        for (int u = 0; u < 8; ++u) { w[u] = __expf(s4[u] - m); sum += w[u]; }
        float inv = 1.0f / sum;
#pragma unroll
        for (int u = 0; u < 8; ++u) { wgt[u] = w[u] * inv; widx[u] = si4[u]; }
    }
    __syncthreads();
    {   // F: weighted gather
        float wv[8]; int ix[8];
#pragma unroll
        for (int u = 0; u < 8; ++u) { wv[u] = wgt[u]; ix[u] = widx[u]; }
        float4 o = make_float4(0.f, 0.f, 0.f, 0.f);
#pragma unroll
        for (int u = 0; u < 8; ++u) {
            float4 r = ((const float4*)(memb + (size_t)ix[u] * NC))[tid];
            o.x = fmaf(wv[u], r.x, o.x);
            o.y = fmaf(wv[u], r.y, o.y);
            o.z = fmaf(wv[u], r.z, o.z);
            o.w = fmaf(wv[u], r.w, o.w);
        }
        ((float4*)(out + (size_t)b * NC))[tid] = o;
    }
}

extern "C" void kernel_launch(void* const* d_in, const int* in_sizes, int n_in,
                              void* d_out, int out_size, void* d_ws, size_t ws_size,
                              hipStream_t stream) {
    const float* seg  = (const float*)d_in[0];
    const float* Wq   = (const float*)d_in[1];
    const float* bq   = (const float*)d_in[2];
    const float* memb = (const float*)d_in[3];
    float* ws = (float*)d_ws;
    float* part  = ws + OFF_PART;
    float* mean  = ws + OFF_MEAN;
    float* q     = ws + OFF_Q;
    s16x8* qb    = (s16x8*)(ws + OFF_QB);
    float* candS = ws + OFF_CS;           // overlays part (safe: part dead by then)
    int*   candI = (int*)(ws + OFF_CI);
    float* out = (float*)d_out;

    mean_partial_k<<<NB * 32, 256, 0, stream>>>(seg, part);
    mean_finalize_k<<<(NB * NC) / 256, 256, 0, stream>>>(part, mean);
    qproj_k<<<512, 256, 0, stream>>>(mean, Wq, bq, q);
    qbf_k<<<16, 256, 0, stream>>>(q, qb);
    scores_mfma_k<<<SBLOCKS, 256, 0, stream>>>(memb, qb, candS, candI);
    finalize_k<<<NB, 256, 0, stream>>>(candS, candI, memb, q, out);
}

// Round 12
// 233.206 us; speedup vs baseline: 3.5905x; 1.0027x over previous
//
#include <hip/hip_runtime.h>
#include <hip/hip_bf16.h>
#include <math.h>

#define NB 32
#define NT 2048
#define NC 1024
#define NM 131072
#define TOPK 8
#define MBLK 64             // m rows per score block
#define SBLOCKS (NM / MBLK) // 2048

typedef __attribute__((ext_vector_type(8))) short s16x8;   // 8 bf16 (4 VGPR)
typedef __attribute__((ext_vector_type(4))) float f32x4;   // MFMA acc
typedef __attribute__((ext_vector_type(4))) int i32x4;

// ws layout (float offsets). candS/candI OVERLAY part (part dead after mean_finalize_k).
#define OFF_PART 0
#define OFF_CS   0                   // 524288 floats
#define OFF_CI   524288              // 524288 ints  (ends 1048576 = part size)
#define OFF_MEAN 1048576
#define OFF_Q    (OFF_MEAN + 32768)
#define OFF_QB   (OFF_Q + 32768)     // 4096 s16x8 = 64 KB

__device__ __forceinline__ unsigned short f2bf(float f) {
    // RNE f32 -> bf16 (finite inputs) — used only in qbf precompute
    unsigned u = __float_as_uint(f);
    unsigned r = (u + 0x7FFFu + ((u >> 16) & 1u)) >> 16;
    return (unsigned short)r;
}

__global__ __launch_bounds__(256) void mean_partial_k(const float* __restrict__ seg,
                                                      float* __restrict__ part) {
    int blk = blockIdx.x;            // 1024 = 32 b * 32 tc
    int b = blk >> 5, tc = blk & 31;
    int tid = threadIdx.x;
    const float4* src = (const float4*)(seg + ((size_t)b * NT + (size_t)tc * 64) * NC);
    float4 acc = make_float4(0.f, 0.f, 0.f, 0.f);
#pragma unroll 4
    for (int t = 0; t < 64; ++t) {
        float4 v = src[(size_t)t * 256 + tid];
        acc.x += v.x; acc.y += v.y; acc.z += v.z; acc.w += v.w;
    }
    ((float4*)(part + ((size_t)b * 32 + tc) * NC))[tid] = acc;
}

__global__ __launch_bounds__(256) void mean_finalize_k(const float* __restrict__ part,
                                                       float* __restrict__ mean) {
    int i = blockIdx.x * 256 + threadIdx.x;   // 32768
    int b = i >> 10, c = i & 1023;
    float s = 0.f;
#pragma unroll
    for (int tc = 0; tc < 32; ++tc) s += part[((size_t)b * 32 + tc) * NC + c];
    mean[i] = s * (1.0f / NT);
}

__global__ __launch_bounds__(256) void qproj_k(const float* __restrict__ mean,
                                               const float* __restrict__ Wq,
                                               const float* __restrict__ bq,
                                               float* __restrict__ q) {
    int wave = (blockIdx.x * 256 + threadIdx.x) >> 6;   // 2048 waves
    int lane = threadIdx.x & 63;
    int o0 = wave * 16;
    for (int j = 0; j < 16; ++j) {
        int o = o0 + j;                 // < 32768
        int b = o >> 10, i = o & 1023;
        const float4* wr = (const float4*)(Wq + (size_t)i * NC);
        const float4* mr = (const float4*)(mean + (size_t)b * NC);
        float acc = 0.f;
#pragma unroll
        for (int e = 0; e < 4; ++e) {
            float4 w4 = wr[lane * 4 + e];
            float4 m4 = mr[lane * 4 + e];
            acc += w4.x * m4.x + w4.y * m4.y + w4.z * m4.z + w4.w * m4.w;
        }
#pragma unroll
        for (int off = 32; off; off >>= 1) acc += __shfl_xor(acc, off);
        if (lane == 0) q[o] = acc + bq[i];
    }
}

// Build B-fragments: qb[(ks*2+n)*64 + lane][e] = bf16(q[n*16+(lane&15)][ks*32+(lane>>4)*8+e])
__global__ __launch_bounds__(256) void qbf_k(const float* __restrict__ q,
                                             s16x8* __restrict__ qb) {
    int idx = blockIdx.x * 256 + threadIdx.x;   // 4096
    int lane = idx & 63, n = (idx >> 6) & 1, ks = idx >> 7;
    int b = n * 16 + (lane & 15);
    int k0 = ks * 32 + ((lane >> 4) << 3);
    s16x8 v;
#pragma unroll
    for (int e = 0; e < 8; ++e) v[e] = (short)f2bf(q[(size_t)b * NC + k0 + e]);
    qb[idx] = v;
}

// branchless top-8 insert with index (finalize)
#define BUBBLE8(v, vi, s, si)                                   \
    {                                                           \
        float _v = (v); int _vi = (vi);                         \
        _Pragma("unroll")                                       \
        for (int _u = 0; _u < 8; ++_u) {                        \
            bool _gt = _v > s[_u];                              \
            float _ts = _gt ? _v : s[_u];                       \
            int _ti = _gt ? _vi : si[_u];                       \
            _v = _gt ? s[_u] : _v;                              \
            _vi = _gt ? si[_u] : _vi;                           \
            s[_u] = _ts; si[_u] = _ti;                          \
        }                                                       \
    }

// float-only top-8 insert (index embedded in low mantissa bits)
#define BUBBLE8F(v, s)                                          \
    {                                                           \
        float _v = (v);                                         \
        _Pragma("unroll")                                       \
        for (int _u = 0; _u < 8; ++_u) {                        \
            bool _gt = _v > s[_u];                              \
            float _ts = _gt ? _v : s[_u];                       \
            _v = _gt ? s[_u] : _v;                              \
            s[_u] = _ts;                                        \
        }                                                       \
    }

// bf16 MFMA approx scores + per-block top-8/b filter. Block = 64 m x 32 b,
// 4 waves (16 rows each). grid 2048, launch_bounds(256,8) -> target 32 waves/CU
// (needs VGPR<=64). A: global->reg, bf16-truncate via v_perm; A and qb both
// register-prefetched one ks ahead, pinned with sched_barrier. LDS 11.5 KB:
// candidate lists are float-only, local row id embedded in low mantissa bits.
__global__ __launch_bounds__(256, 8) void scores_mfma_k(const float* __restrict__ memb,
                                                        const s16x8* __restrict__ qb,
                                                        float* __restrict__ candS,
                                                        int* __restrict__ candI) {
    __shared__ __align__(16) float smemf[2880];   // scores [32][65] | cs [256][9] | csA [64][9]
    int tid = threadIdx.x, lane = tid & 63, wid = tid >> 6;
    int m0 = blockIdx.x * MBLK;

    f32x4 acc[2];
    acc[0] = (f32x4){0.f, 0.f, 0.f, 0.f};
    acc[1] = (f32x4){0.f, 0.f, 0.f, 0.f};

    const unsigned* abase = (const unsigned*)(memb
        + (size_t)(m0 + wid * 16 + (lane & 15)) * NC + ((lane >> 4) << 3));
    uint4 lo0 = *(const uint4*)(abase);
    uint4 hi0 = *(const uint4*)(abase + 4);
    s16x8 bf0 = qb[lane];
    s16x8 bf1 = qb[64 + lane];

    for (int ks = 0; ks < 32; ++ks) {
        uint4 lo1, hi1; s16x8 nb0, nb1;
        if (ks < 31) {
            lo1 = *(const uint4*)(abase + (ks + 1) * 32);
            hi1 = *(const uint4*)(abase + (ks + 1) * 32 + 4);
            nb0 = qb[((ks + 1) * 2 + 0) * 64 + lane];
            nb1 = qb[((ks + 1) * 2 + 1) * 64 + lane];
        }
        __builtin_amdgcn_sched_barrier(0);   // pin prefetch issues above compute
        i32x4 ai;
        ai[0] = __builtin_amdgcn_perm(lo0.y, lo0.x, 0x07060302u);  // bf(x)|bf(y)<<16
        ai[1] = __builtin_amdgcn_perm(lo0.w, lo0.z, 0x07060302u);
        ai[2] = __builtin_amdgcn_perm(hi0.y, hi0.x, 0x07060302u);
        ai[3] = __builtin_amdgcn_perm(hi0.w, hi0.z, 0x07060302u);
        s16x8 a = __builtin_bit_cast(s16x8, ai);
        acc[0] = __builtin_amdgcn_mfma_f32_16x16x32_bf16(a, bf0, acc[0], 0, 0, 0);
        acc[1] = __builtin_amdgcn_mfma_f32_16x16x32_bf16(a, bf1, acc[1], 0, 0, 0);
        lo0 = lo1; hi0 = hi1; bf0 = nb0; bf1 = nb1;
    }

    // D layout (m89-verified): col = lane&15 (b within n-tile), row = (lane>>4)*4+j
#pragma unroll
    for (int n = 0; n < 2; ++n)
#pragma unroll
        for (int j = 0; j < 4; ++j) {
            int bb = n * 16 + (lane & 15);
            int mm = wid * 16 + ((lane >> 4) << 2) + j;
            smemf[bb * 65 + mm] = acc[n][j] * 0.03125f;
        }
    __syncthreads();

    // per-b top-8 (approx): 8 threads per b, each scans 8 of 64 scores.
    // Identity embedded: low 8 mantissa bits := local row (0..63).
    {
        int b = tid >> 3, p = tid & 7;
        float s[8];
#pragma unroll
        for (int u = 0; u < 8; ++u) s[u] = -INFINITY;
#pragma unroll
        for (int j = 0; j < 8; ++j) {
            int ml = (p + j * 8 + b * 4) & 63;
            float v = smemf[b * 65 + ml];
            unsigned uu = (__float_as_uint(v) & ~0xFFu) | (unsigned)ml;
            BUBBLE8F(__uint_as_float(uu), s);
        }
        __syncthreads();   // scores consumed; overlay cs lists
        float* cs = smemf;                    // [256][9] at [0,2304)
#pragma unroll
        for (int u = 0; u < 8; ++u) cs[tid * 9 + u] = s[u];
        __syncthreads();
        float* csA = smemf + 2304;            // [64][9] -> ends 2880
        if (tid < 64) {
            float s2[8];
#pragma unroll
            for (int u = 0; u < 8; ++u) s2[u] = -INFINITY;
            int t0 = (tid >> 1) * 8 + (tid & 1) * 4;
            for (int tt = 0; tt < 4; ++tt)
#pragma unroll
                for (int u = 0; u < 8; ++u)
                    BUBBLE8F(cs[(t0 + tt) * 9 + u], s2);
#pragma unroll
            for (int u = 0; u < 8; ++u) csA[tid * 9 + u] = s2[u];
        }
        __syncthreads();
        if (tid < 32) {
            float s3[8];
#pragma unroll
            for (int u = 0; u < 8; ++u) s3[u] = -INFINITY;
            for (int j = 0; j < 16; ++j)
                BUBBLE8F(csA[(tid * 2 + (j >> 3)) * 9 + (j & 7)], s3);
#pragma unroll
            for (int u = 0; u < 8; ++u) {
                candS[((size_t)tid * SBLOCKS + blockIdx.x) * 8 + u] = s3[u];
                candI[((size_t)tid * SBLOCKS + blockIdx.x) * 8 + u] =
                    m0 + (int)(__float_as_uint(s3[u]) & 0xFFu);
            }
        }
    }
}

// Per b: merge 16384 approx candidates -> 64 survivors -> EXACT f32 rescore ->
// exact top-8 + softmax + weighted gather.
__global__ __launch_bounds__(256) void finalize_k(const float* __restrict__ candS,
                                                  const int* __restrict__ candI,
                                                  const float* __restrict__ memb,
                                                  const float* __restrict__ q,
                                                  float* __restrict__ out) {
    __shared__ float cs[256 * 9];
    __shared__ int ci[256 * 9];
    __shared__ float csA[64 * 9];
    __shared__ int ciA[64 * 9];
    __shared__ float exsc[64];
    __shared__ int exid[64];
    __shared__ float wgt[8];
    __shared__ int widx[8];
    int b = blockIdx.x, tid = threadIdx.x;
    const float* S = candS + (size_t)b * (SBLOCKS * 8);
    const int* I = candI + (size_t)b * (SBLOCKS * 8);

    {   // A: 256 threads x 64 candidates
        float s[8]; int si[8];
#pragma unroll
        for (int u = 0; u < 8; ++u) { s[u] = -INFINITY; si[u] = -1; }
        for (int j = 0; j < 64; ++j)
            BUBBLE8(S[tid * 64 + j], I[tid * 64 + j], s, si);
#pragma unroll
        for (int u = 0; u < 8; ++u) { cs[tid * 9 + u] = s[u]; ci[tid * 9 + u] = si[u]; }
    }
    __syncthreads();
    if (tid < 64) {   // B: merge 4 lists
        float s[8]; int si[8];
#pragma unroll
        for (int u = 0; u < 8; ++u) { s[u] = -INFINITY; si[u] = -1; }
        for (int tt = 0; tt < 4; ++tt)
#pragma unroll
            for (int u = 0; u < 8; ++u)
                BUBBLE8(cs[(tid * 4 + tt) * 9 + u], ci[(tid * 4 + tt) * 9 + u], s, si);
#pragma unroll
        for (int u = 0; u < 8; ++u) { csA[tid * 9 + u] = s[u]; ciA[tid * 9 + u] = si[u]; }
    }
    __syncthreads();
    if (tid < 8) {    // C: merge 8 lists -> 8 survivors each (64 total, superset of true top-8)
        float s[8]; int si[8];
#pragma unroll
        for (int u = 0; u < 8; ++u) { s[u] = -INFINITY; si[u] = -1; }
        for (int tt = 0; tt < 8; ++tt)
#pragma unroll
            for (int u = 0; u < 8; ++u)
                BUBBLE8(csA[(tid * 8 + tt) * 9 + u], ciA[(tid * 8 + tt) * 9 + u], s, si);
#pragma unroll
        for (int u = 0; u < 8; ++u) exid[tid * 8 + u] = si[u];
    }
    __syncthreads();
    {   // D: exact f32 rescore of 64 survivors; wave w -> candidates w*16..+15
        int w = tid >> 6, lane = tid & 63;
        const float4* qr = (const float4*)(q + (size_t)b * NC);
        for (int i = 0; i < 16; ++i) {
            int c = w * 16 + i;
            int row = exid[c];
            const float4* mr = (const float4*)(memb + (size_t)row * NC);
            float d = 0.f;
#pragma unroll
            for (int e = 0; e < 4; ++e) {
                float4 m4 = mr[e * 64 + lane];
                float4 q4 = qr[e * 64 + lane];
                d += m4.x * q4.x + m4.y * q4.y + m4.z * q4.z + m4.w * q4.w;
            }
#pragma unroll
            for (int off = 32; off; off >>= 1) d += __shfl_xor(d, off);
            if (lane == 0) exsc[c] = d * 0.03125f;
        }
    }
    __syncthreads();
    if (tid == 0) {   // E: exact top-8 of 64 + softmax
        float s4[8]; int si4[8];
#pragma unroll
        for (int u = 0; u < 8; ++u) { s4[u] = -INFINITY; si4[u] = -1; }
        for (int j = 0; j < 64; ++j)
            BUBBLE8(exsc[j], exid[j], s4, si4);
        float m = s4[0], sum = 0.f, w[8];
#pragma unroll
        for (int u = 0; u < 8; ++u) { w[u] = __expf(s4[u] - m); sum += w[u]; }
        float inv = 1.0f / sum;
#pragma unroll
        for (int u = 0; u < 8; ++u) { wgt[u] = w[u] * inv; widx[u] = si4[u]; }
    }
    __syncthreads();
    {   // F: weighted gather
        float wv[8]; int ix[8];
#pragma unroll
        for (int u = 0; u < 8; ++u) { wv[u] = wgt[u]; ix[u] = widx[u]; }
        float4 o = make_float4(0.f, 0.f, 0.f, 0.f);
#pragma unroll
        for (int u = 0; u < 8; ++u) {
            float4 r = ((const float4*)(memb + (size_t)ix[u] * NC))[tid];
            o.x = fmaf(wv[u], r.x, o.x);
            o.y = fmaf(wv[u], r.y, o.y);
            o.z = fmaf(wv[u], r.z, o.z);
            o.w = fmaf(wv[u], r.w, o.w);
        }
        ((float4*)(out + (size_t)b * NC))[tid] = o;
    }
}

extern "C" void kernel_launch(void* const* d_in, const int* in_sizes, int n_in,
                              void* d_out, int out_size, void* d_ws, size_t ws_size,
                              hipStream_t stream) {
    const float* seg  = (const float*)d_in[0];
    const float* Wq   = (const float*)d_in[1];
    const float* bq   = (const float*)d_in[2];
    const float* memb = (const float*)d_in[3];
    float* ws = (float*)d_ws;
    float* part  = ws + OFF_PART;
    float* mean  = ws + OFF_MEAN;
    float* q     = ws + OFF_Q;
    s16x8* qb    = (s16x8*)(ws + OFF_QB);
    float* candS = ws + OFF_CS;           // overlays part (safe: part dead by then)
    int*   candI = (int*)(ws + OFF_CI);
    float* out = (float*)d_out;

    mean_partial_k<<<NB * 32, 256, 0, stream>>>(seg, part);
    mean_finalize_k<<<(NB * NC) / 256, 256, 0, stream>>>(part, mean);
    qproj_k<<<512, 256, 0, stream>>>(mean, Wq, bq, q);
    qbf_k<<<16, 256, 0, stream>>>(q, qb);
    scores_mfma_k<<<SBLOCKS, 256, 0, stream>>>(memb, qb, candS, candI);
    finalize_k<<<NB, 256, 0, stream>>>(candS, candI, memb, q, out);
}

// Round 13
// 213.621 us; speedup vs baseline: 3.9196x; 1.0917x over previous
//
#include <hip/hip_runtime.h>
#include <hip/hip_bf16.h>
#include <math.h>

#define NB 32
#define NT 2048
#define NC 1024
#define NM 131072
#define TOPK 8
#define PANELS 8            // panels per block (16 rows each)
#define NSB 1024            // scores grid
#define SLOTF 260           // padded LDS slot (floats) = 1040 B, 2-way banks

typedef __attribute__((ext_vector_type(8))) short s16x8;   // 8 bf16 (4 VGPR)
typedef __attribute__((ext_vector_type(4))) float f32x4;   // MFMA acc
typedef __attribute__((ext_vector_type(4))) int i32x4;

// ws layout (float offsets). candS/candI OVERLAY part (part dead after mean_finalize_k).
#define OFF_PART 0
#define OFF_CS   0                   // 32*8192 = 262144 floats
#define OFF_CI   262144              // 262144 ints (ends 524288 < part's 1048576)
#define OFF_MEAN 1048576
#define OFF_Q    (OFF_MEAN + 32768)
#define OFF_QB   (OFF_Q + 32768)     // 4096 s16x8 = 64 KB

__device__ __forceinline__ unsigned short f2bf(float f) {
    unsigned u = __float_as_uint(f);
    unsigned r = (u + 0x7FFFu + ((u >> 16) & 1u)) >> 16;
    return (unsigned short)r;
}

__device__ __forceinline__ void gl_lds16(const float* g, float* l) {
    // one instruction: 64 lanes x 16B -> LDS base + lane*16 (contiguous 1 KB)
    __builtin_amdgcn_global_load_lds((const __attribute__((address_space(1))) void*)g,
                                     (__attribute__((address_space(3))) void*)l, 16, 0, 0);
}

__global__ __launch_bounds__(256) void mean_partial_k(const float* __restrict__ seg,
                                                      float* __restrict__ part) {
    int blk = blockIdx.x;            // 1024 = 32 b * 32 tc
    int b = blk >> 5, tc = blk & 31;
    int tid = threadIdx.x;
    const float4* src = (const float4*)(seg + ((size_t)b * NT + (size_t)tc * 64) * NC);
    float4 acc = make_float4(0.f, 0.f, 0.f, 0.f);
#pragma unroll 4
    for (int t = 0; t < 64; ++t) {
        float4 v = src[(size_t)t * 256 + tid];
        acc.x += v.x; acc.y += v.y; acc.z += v.z; acc.w += v.w;
    }
    ((float4*)(part + ((size_t)b * 32 + tc) * NC))[tid] = acc;
}

__global__ __launch_bounds__(256) void mean_finalize_k(const float* __restrict__ part,
                                                       float* __restrict__ mean) {
    int i = blockIdx.x * 256 + threadIdx.x;   // 32768
    int b = i >> 10, c = i & 1023;
    float s = 0.f;
#pragma unroll
    for (int tc = 0; tc < 32; ++tc) s += part[((size_t)b * 32 + tc) * NC + c];
    mean[i] = s * (1.0f / NT);
}

__global__ __launch_bounds__(256) void qproj_k(const float* __restrict__ mean,
                                               const float* __restrict__ Wq,
                                               const float* __restrict__ bq,
                                               float* __restrict__ q) {
    int wave = (blockIdx.x * 256 + threadIdx.x) >> 6;   // 2048 waves
    int lane = threadIdx.x & 63;
    int o0 = wave * 16;
    for (int j = 0; j < 16; ++j) {
        int o = o0 + j;                 // < 32768
        int b = o >> 10, i = o & 1023;
        const float4* wr = (const float4*)(Wq + (size_t)i * NC);
        const float4* mr = (const float4*)(mean + (size_t)b * NC);
        float acc = 0.f;
#pragma unroll
        for (int e = 0; e < 4; ++e) {
            float4 w4 = wr[lane * 4 + e];
            float4 m4 = mr[lane * 4 + e];
            acc += w4.x * m4.x + w4.y * m4.y + w4.z * m4.z + w4.w * m4.w;
        }
#pragma unroll
        for (int off = 32; off; off >>= 1) acc += __shfl_xor(acc, off);
        if (lane == 0) q[o] = acc + bq[i];
    }
}

// qb[(ksg*2+n)*64 + lane][e] = bf16(q[n*16+(lane&15)][ksg*32+(lane>>4)*8+e])
__global__ __launch_bounds__(256) void qbf_k(const float* __restrict__ q,
                                             s16x8* __restrict__ qb) {
    int idx = blockIdx.x * 256 + threadIdx.x;   // 4096
    int lane = idx & 63, n = (idx >> 6) & 1, ks = idx >> 7;
    int b = n * 16 + (lane & 15);
    int k0 = ks * 32 + ((lane >> 4) << 3);
    s16x8 v;
#pragma unroll
    for (int e = 0; e < 8; ++e) v[e] = (short)f2bf(q[(size_t)b * NC + k0 + e]);
    qb[idx] = v;
}

#define BUBBLE8(v, vi, s, si)                                   \
    {                                                           \
        float _v = (v); int _vi = (vi);                         \
        _Pragma("unroll")                                       \
        for (int _u = 0; _u < 8; ++_u) {                        \
            bool _gt = _v > s[_u];                               \
            float _ts = _gt ? _v : s[_u];                       \
            int _ti = _gt ? _vi : si[_u];                       \
            _v = _gt ? s[_u] : _v;                              \
            _vi = _gt ? si[_u] : _vi;                           \
            s[_u] = _ts; si[_u] = _ti;                          \
        }                                                       \
    }

// Sequential-stream MFMA scores. 1 wave/block, 8 panels x 16 rows, grid 1024
// (4 blocks/CU). Per chunk (256 floats/row): 16x global_load_lds, each moving
// one row's contiguous 1 KB -> block fetch stream is sequential 64 KB chunks
// (DRAM page-friendly). LDS double-buffer, padded slots. K-loop vmem = 16 qb
// loads + 16 tile DMAs per chunk, explicit vmcnt(0); next chunk issued before
// compute. Running per-lane-pair top-8 across panels in registers; one store
// burst per block.
__global__ __launch_bounds__(64) void scores_mfma_k(const float* __restrict__ memb,
                                                    const s16x8* __restrict__ qb,
                                                    float* __restrict__ candS,
                                                    int* __restrict__ candI) {
    __shared__ __align__(16) float tiles[2 * 16 * SLOTF];   // 33,280 B
    __shared__ __align__(16) float sc[32 * 17];             // 2,176 B
    int lane = threadIdx.x;
    size_t mb0 = (size_t)blockIdx.x * (PANELS * 16);

    float s8[8]; int i8[8];
#pragma unroll
    for (int u = 0; u < 8; ++u) { s8[u] = -INFINITY; i8[u] = -1; }

#define TISSUE(t_) { int p_ = (t_) >> 2, c_ = (t_) & 3;                               \
    const float* rb_ = memb + (mb0 + p_ * 16) * NC + c_ * 256 + lane * 4;             \
    float* lb_ = tiles + ((t_) & 1) * (16 * SLOTF);                                   \
    _Pragma("unroll") for (int i_ = 0; i_ < 16; ++i_)                                 \
        gl_lds16(rb_ + (size_t)i_ * NC, lb_ + i_ * SLOTF); }

    f32x4 acc0 = (f32x4){0.f, 0.f, 0.f, 0.f};
    f32x4 acc1 = (f32x4){0.f, 0.f, 0.f, 0.f};

    TISSUE(0);
    for (int t = 0; t < PANELS * 4; ++t) {
        int c = t & 3;
        // qb fragments for this chunk (same k-range every panel; L2-hot)
        s16x8 qf[16];
#pragma unroll
        for (int k = 0; k < 8; ++k) {
            qf[2 * k]     = qb[((c * 8 + k) * 2 + 0) * 64 + lane];
            qf[2 * k + 1] = qb[((c * 8 + k) * 2 + 1) * 64 + lane];
        }
        asm volatile("s_waitcnt vmcnt(0)" ::: "memory");   // tile t + qf landed
        __builtin_amdgcn_sched_barrier(0);
        if (t + 1 < PANELS * 4) TISSUE(t + 1);             // stream next chunk during compute

        const float* lanebase = tiles + (t & 1) * (16 * SLOTF)
                              + (lane & 15) * SLOTF + ((lane >> 4) << 3);
#pragma unroll
        for (int ks = 0; ks < 8; ++ks) {
            uint4 lo = *(const uint4*)(lanebase + ks * 32);
            uint4 hi = *(const uint4*)(lanebase + ks * 32 + 4);
            i32x4 ai;
            ai[0] = __builtin_amdgcn_perm(lo.y, lo.x, 0x07060302u);
            ai[1] = __builtin_amdgcn_perm(lo.w, lo.z, 0x07060302u);
            ai[2] = __builtin_amdgcn_perm(hi.y, hi.x, 0x07060302u);
            ai[3] = __builtin_amdgcn_perm(hi.w, hi.z, 0x07060302u);
            s16x8 a = __builtin_bit_cast(s16x8, ai);
            acc0 = __builtin_amdgcn_mfma_f32_16x16x32_bf16(a, qf[2 * ks], acc0, 0, 0, 0);
            acc1 = __builtin_amdgcn_mfma_f32_16x16x32_bf16(a, qf[2 * ks + 1], acc1, 0, 0, 0);
        }

        if (c == 3) {   // panel done: scores -> sc, scan into running top-8
            int p = t >> 2;
            // D layout (m89): col=lane&15 -> b(n*16+..), row=(lane>>4)*4+j -> m
#pragma unroll
            for (int j = 0; j < 4; ++j) {
                sc[(0 * 16 + (lane & 15)) * 17 + ((lane >> 4) << 2) + j] = acc0[j];
                sc[(1 * 16 + (lane & 15)) * 17 + ((lane >> 4) << 2) + j] = acc1[j];
            }
            asm volatile("s_waitcnt lgkmcnt(0)" ::: "memory");
            __builtin_amdgcn_sched_barrier(0);
            int b = lane >> 1, p2 = lane & 1;
            int midx0 = mb0 + p * 16;
#pragma unroll
            for (int j = 0; j < 8; ++j) {
                int m = ((b + j) & 7) + p2 * 8;
                float v = sc[b * 17 + m];
                BUBBLE8(v, midx0 + m, s8, i8);
            }
            asm volatile("s_waitcnt lgkmcnt(0)" ::: "memory");
            __builtin_amdgcn_sched_barrier(0);
            acc0 = (f32x4){0.f, 0.f, 0.f, 0.f};
            acc1 = (f32x4){0.f, 0.f, 0.f, 0.f};
        }
    }
#undef TISSUE

    // merge lane pair (b = lane>>1 identical for the pair), lane&1==0 writes
    {
        float ov[8]; int oi[8];
#pragma unroll
        for (int u = 0; u < 8; ++u) { ov[u] = s8[u]; oi[u] = i8[u]; }
#pragma unroll
        for (int u = 0; u < 8; ++u) {
            float pv = __shfl_xor(ov[u], 1);
            int pi = __shfl_xor(oi[u], 1);
            BUBBLE8(pv, pi, s8, i8);
        }
        if ((lane & 1) == 0) {
            int b = lane >> 1;
#pragma unroll
            for (int u = 0; u < 8; ++u) {
                candS[(size_t)b * (NSB * 8) + blockIdx.x * 8 + u] = s8[u] * 0.03125f;
                candI[(size_t)b * (NSB * 8) + blockIdx.x * 8 + u] = i8[u];
            }
        }
    }
}

// Per b: merge 8192 approx candidates -> 64 survivors -> EXACT f32 rescore ->
// exact top-8 + softmax + weighted gather.
__global__ __launch_bounds__(256) void finalize_k(const float* __restrict__ candS,
                                                  const int* __restrict__ candI,
                                                  const float* __restrict__ memb,
                                                  const float* __restrict__ q,
                                                  float* __restrict__ out) {
    __shared__ float cs[256 * 9];
    __shared__ int ci[256 * 9];
    __shared__ float csA[64 * 9];
    __shared__ int ciA[64 * 9];
    __shared__ float exsc[64];
    __shared__ int exid[64];
    __shared__ float wgt[8];
    __shared__ int widx[8];
    int b = blockIdx.x, tid = threadIdx.x;
    const float* S = candS + (size_t)b * (NSB * 8);
    const int* I = candI + (size_t)b * (NSB * 8);

    {   // A: 256 threads x 32 candidates
        float s[8]; int si[8];
#pragma unroll
        for (int u = 0; u < 8; ++u) { s[u] = -INFINITY; si[u] = -1; }
        for (int j = 0; j < 32; ++j)
            BUBBLE8(S[tid * 32 + j], I[tid * 32 + j], s, si);
#pragma unroll
        for (int u = 0; u < 8; ++u) { cs[tid * 9 + u] = s[u]; ci[tid * 9 + u] = si[u]; }
    }
    __syncthreads();
    if (tid < 64) {   // B: merge 4 lists
        float s[8]; int si[8];
#pragma unroll
        for (int u = 0; u < 8; ++u) { s[u] = -INFINITY; si[u] = -1; }
        for (int tt = 0; tt < 4; ++tt)
#pragma unroll
            for (int u = 0; u < 8; ++u)
                BUBBLE8(cs[(tid * 4 + tt) * 9 + u], ci[(tid * 4 + tt) * 9 + u], s, si);
#pragma unroll
        for (int u = 0; u < 8; ++u) { csA[tid * 9 + u] = s[u]; ciA[tid * 9 + u] = si[u]; }
    }
    __syncthreads();
    if (tid < 8) {    // C: merge 8 lists -> 64 survivors (superset of true top-8)
        float s[8]; int si[8];
#pragma unroll
        for (int u = 0; u < 8; ++u) { s[u] = -INFINITY; si[u] = -1; }
        for (int tt = 0; tt < 8; ++tt)
#pragma unroll
            for (int u = 0; u < 8; ++u)
                BUBBLE8(csA[(tid * 8 + tt) * 9 + u], ciA[(tid * 8 + tt) * 9 + u], s, si);
#pragma unroll
        for (int u = 0; u < 8; ++u) exid[tid * 8 + u] = si[u];
    }
    __syncthreads();
    {   // D: exact f32 rescore; wave w -> candidates w*16..+15
        int w = tid >> 6, lane = tid & 63;
        const float4* qr = (const float4*)(q + (size_t)b * NC);
        for (int i = 0; i < 16; ++i) {
            int c = w * 16 + i;
            int row = exid[c];
            const float4* mr = (const float4*)(memb + (size_t)row * NC);
            float d = 0.f;
#pragma unroll
            for (int e = 0; e < 4; ++e) {
                float4 m4 = mr[e * 64 + lane];
                float4 q4 = qr[e * 64 + lane];
                d += m4.x * q4.x + m4.y * q4.y + m4.z * q4.z + m4.w * q4.w;
            }
#pragma unroll
            for (int off = 32; off; off >>= 1) d += __shfl_xor(d, off);
            if (lane == 0) exsc[c] = d * 0.03125f;
        }
    }
    __syncthreads();
    if (tid == 0) {   // E: exact top-8 of 64 + softmax
        float s4[8]; int si4[8];
#pragma unroll
        for (int u = 0; u < 8; ++u) { s4[u] = -INFINITY; si4[u] = -1; }
        for (int j = 0; j < 64; ++j)
            BUBBLE8(exsc[j], exid[j], s4, si4);
        float m = s4[0], sum = 0.f, w[8];
#pragma unroll
        for (int u = 0; u < 8; ++u) { w[u] = __expf(s4[u] - m); sum += w[u]; }
        float inv = 1.0f / sum;
#pragma unroll
        for (int u = 0; u < 8; ++u) { wgt[u] = w[u] * inv; widx[u] = si4[u]; }
    }
    __syncthreads();
    {   // F: weighted gather
        float wv[8]; int ix[8];
#pragma unroll
        for (int u = 0; u < 8; ++u) { wv[u] = wgt[u]; ix[u] = widx[u]; }
        float4 o = make_float4(0.f, 0.f, 0.f, 0.f);
#pragma unroll
        for (int u = 0; u < 8; ++u) {
            float4 r = ((const float4*)(memb + (size_t)ix[u] * NC))[tid];
            o.x = fmaf(wv[u], r.x, o.x);
            o.y = fmaf(wv[u], r.y, o.y);
            o.z = fmaf(wv[u], r.z, o.z);
            o.w = fmaf(wv[u], r.w, o.w);
        }
        ((float4*)(out + (size_t)b * NC))[tid] = o;
    }
}

extern "C" void kernel_launch(void* const* d_in, const int* in_sizes, int n_in,
                              void* d_out, int out_size, void* d_ws, size_t ws_size,
                              hipStream_t stream) {
    const float* seg  = (const float*)d_in[0];
    const float* Wq   = (const float*)d_in[1];
    const float* bq   = (const float*)d_in[2];
    const float* memb = (const float*)d_in[3];
    float* ws = (float*)d_ws;
    float* part  = ws + OFF_PART;
    float* mean  = ws + OFF_MEAN;
    float* q     = ws + OFF_Q;
    s16x8* qb    = (s16x8*)(ws + OFF_QB);
    float* candS = ws + OFF_CS;           // overlays part (safe: part dead by then)
    int*   candI = (int*)(ws + OFF_CI);
    float* out = (float*)d_out;

    mean_partial_k<<<NB * 32, 256, 0, stream>>>(seg, part);
    mean_finalize_k<<<(NB * NC) / 256, 256, 0, stream>>>(part, mean);
    qproj_k<<<512, 256, 0, stream>>>(mean, Wq, bq, q);
    qbf_k<<<16, 256, 0, stream>>>(q, qb);
    scores_mfma_k<<<NSB, 64, 0, stream>>>(memb, qb, candS, candI);
    finalize_k<<<NB, 256, 0, stream>>>(candS, candI, memb, q, out);
}

// Round 14
// 208.910 us; speedup vs baseline: 4.0080x; 1.0226x over previous
//
#include <hip/hip_runtime.h>
#include <hip/hip_bf16.h>
#include <math.h>

#define NB 32
#define NT 2048
#define NC 1024
#define NM 131072
#define TOPK 8
#define PANELS 16           // panels per block (16 rows each) -> 256 rows/block
#define NSB 512             // scores grid
#define NCHUNK (PANELS * 4) // 64 chunks per block
#define SLOTF 260           // padded LDS slot (floats) = 1040 B

typedef __attribute__((ext_vector_type(8))) short s16x8;   // 8 bf16 = 16 B
typedef __attribute__((ext_vector_type(4))) float f32x4;   // MFMA acc
typedef __attribute__((ext_vector_type(4))) int i32x4;

// ws layout (float offsets). candS/candI OVERLAY part (part dead after mean_finalize_k).
#define OFF_PART 0
#define OFF_CS   0                   // 32*512*8 = 131072 floats
#define OFF_CI   131072              // ends 262144 < part's 1048576
#define OFF_MEAN 1048576
#define OFF_Q    (OFF_MEAN + 32768)
#define OFF_QB   (OFF_Q + 32768)     // 4096 s16x8 = 64 KB

__device__ __forceinline__ unsigned short f2bf(float f) {
    unsigned u = __float_as_uint(f);
    unsigned r = (u + 0x7FFFu + ((u >> 16) & 1u)) >> 16;
    return (unsigned short)r;
}

__device__ __forceinline__ void gl_lds16(const float* g, float* l) {
    // one instruction: 64 lanes x 16B -> LDS base + lane*16 (contiguous 1 KB)
    __builtin_amdgcn_global_load_lds((const __attribute__((address_space(1))) void*)g,
                                     (__attribute__((address_space(3))) void*)l, 16, 0, 0);
}

__global__ __launch_bounds__(256) void mean_partial_k(const float* __restrict__ seg,
                                                      float* __restrict__ part) {
    int blk = blockIdx.x;            // 1024 = 32 b * 32 tc
    int b = blk >> 5, tc = blk & 31;
    int tid = threadIdx.x;
    const float4* src = (const float4*)(seg + ((size_t)b * NT + (size_t)tc * 64) * NC);
    float4 acc = make_float4(0.f, 0.f, 0.f, 0.f);
#pragma unroll 4
    for (int t = 0; t < 64; ++t) {
        float4 v = src[(size_t)t * 256 + tid];
        acc.x += v.x; acc.y += v.y; acc.z += v.z; acc.w += v.w;
    }
    ((float4*)(part + ((size_t)b * 32 + tc) * NC))[tid] = acc;
}

__global__ __launch_bounds__(256) void mean_finalize_k(const float* __restrict__ part,
                                                       float* __restrict__ mean) {
    int i = blockIdx.x * 256 + threadIdx.x;   // 32768
    int b = i >> 10, c = i & 1023;
    float s = 0.f;
#pragma unroll
    for (int tc = 0; tc < 32; ++tc) s += part[((size_t)b * 32 + tc) * NC + c];
    mean[i] = s * (1.0f / NT);
}

__global__ __launch_bounds__(256) void qproj_k(const float* __restrict__ mean,
                                               const float* __restrict__ Wq,
                                               const float* __restrict__ bq,
                                               float* __restrict__ q) {
    int wave = (blockIdx.x * 256 + threadIdx.x) >> 6;   // 2048 waves
    int lane = threadIdx.x & 63;
    int o0 = wave * 16;
    for (int j = 0; j < 16; ++j) {
        int o = o0 + j;                 // < 32768
        int b = o >> 10, i = o & 1023;
        const float4* wr = (const float4*)(Wq + (size_t)i * NC);
        const float4* mr = (const float4*)(mean + (size_t)b * NC);
        float acc = 0.f;
#pragma unroll
        for (int e = 0; e < 4; ++e) {
            float4 w4 = wr[lane * 4 + e];
            float4 m4 = mr[lane * 4 + e];
            acc += w4.x * m4.x + w4.y * m4.y + w4.z * m4.z + w4.w * m4.w;
        }
#pragma unroll
        for (int off = 32; off; off >>= 1) acc += __shfl_xor(acc, off);
        if (lane == 0) q[o] = acc + bq[i];
    }
}

// qb[(ksg*2+n)*64 + lane][e] = bf16(q[n*16+(lane&15)][ksg*32+(lane>>4)*8+e])
__global__ __launch_bounds__(256) void qbf_k(const float* __restrict__ q,
                                             s16x8* __restrict__ qb) {
    int idx = blockIdx.x * 256 + threadIdx.x;   // 4096
    int lane = idx & 63, n = (idx >> 6) & 1, ks = idx >> 7;
    int b = n * 16 + (lane & 15);
    int k0 = ks * 32 + ((lane >> 4) << 3);
    s16x8 v;
#pragma unroll
    for (int e = 0; e < 8; ++e) v[e] = (short)f2bf(q[(size_t)b * NC + k0 + e]);
    qb[idx] = v;
}

#define BUBBLE8(v, vi, s, si)                                   \
    {                                                           \
        float _v = (v); int _vi = (vi);                         \
        _Pragma("unroll")                                       \
        for (int _u = 0; _u < 8; ++_u) {                        \
            bool _gt = _v > s[_u];                               \
            float _ts = _gt ? _v : s[_u];                       \
            int _ti = _gt ? _vi : si[_u];                       \
            _v = _gt ? s[_u] : _v;                              \
            _vi = _gt ? si[_u] : _vi;                           \
            s[_u] = _ts; si[_u] = _ti;                          \
        }                                                       \
    }

// Deep-pipelined sequential-stream MFMA scores. 1 wave/block, 16 panels x 16
// rows, grid 512 (2 blocks/CU, all resident). Counted vmcnt keeps 1-2 tiles +
// qf always in flight (never drains to 0 in the loop). Issue invariant per
// chunk t: [tile t:16][qf t:16][tile t+1:16]; wait vmcnt(16) -> tile t + qf t
// landed, tile t+1 still flying. qfA/qfB static register dbuf (unroll x2);
// launch_bounds(64,1) gives 512-VGPR budget so loads are not sunk.
__global__ __launch_bounds__(64, 1) void scores_mfma_k(const float* __restrict__ memb,
                                                       const s16x8* __restrict__ qb,
                                                       float* __restrict__ candS,
                                                       int* __restrict__ candI) {
    __shared__ __align__(16) float tiles[3 * 16 * SLOTF];   // 49,920 B (triple buffer)
    __shared__ __align__(16) float sc[32 * 17];             // 2,176 B
    int lane = threadIdx.x;
    size_t mb0 = (size_t)blockIdx.x * (PANELS * 16);

    float s8[8]; int i8[8];
#pragma unroll
    for (int u = 0; u < 8; ++u) { s8[u] = -INFINITY; i8[u] = -1; }

#define TISSUE(t_) { int p_ = (t_) >> 2, c_ = (t_) & 3;                               \
    const float* rb_ = memb + (mb0 + p_ * 16) * NC + c_ * 256 + lane * 4;             \
    float* lb_ = tiles + ((t_) % 3) * (16 * SLOTF);                                   \
    _Pragma("unroll") for (int i_ = 0; i_ < 16; ++i_)                                 \
        gl_lds16(rb_ + (size_t)i_ * NC, lb_ + i_ * SLOTF); }

#define QLOAD(dst_, t_) { int c_ = (t_) & 3;                                          \
    _Pragma("unroll") for (int k_ = 0; k_ < 8; ++k_) {                                \
        dst_[2 * k_]     = qb[((c_ * 8 + k_) * 2 + 0) * 64 + lane];                   \
        dst_[2 * k_ + 1] = qb[((c_ * 8 + k_) * 2 + 1) * 64 + lane]; } }

#define COMPUTE(t_, qf_) {                                                            \
    const float* lanebase = tiles + ((t_) % 3) * (16 * SLOTF)                         \
                          + (lane & 15) * SLOTF + ((lane >> 4) << 3);                 \
    _Pragma("unroll") for (int ks = 0; ks < 8; ++ks) {                                \
        uint4 lo = *(const uint4*)(lanebase + ks * 32);                               \
        uint4 hi = *(const uint4*)(lanebase + ks * 32 + 4);                           \
        i32x4 ai;                                                                     \
        ai[0] = __builtin_amdgcn_perm(lo.y, lo.x, 0x07060302u);                       \
        ai[1] = __builtin_amdgcn_perm(lo.w, lo.z, 0x07060302u);                       \
        ai[2] = __builtin_amdgcn_perm(hi.y, hi.x, 0x07060302u);                       \
        ai[3] = __builtin_amdgcn_perm(hi.w, hi.z, 0x07060302u);                       \
        s16x8 a = __builtin_bit_cast(s16x8, ai);                                      \
        acc0 = __builtin_amdgcn_mfma_f32_16x16x32_bf16(a, qf_[2 * ks], acc0, 0, 0, 0);\
        acc1 = __builtin_amdgcn_mfma_f32_16x16x32_bf16(a, qf_[2 * ks + 1], acc1, 0, 0, 0); } \
    if (((t_) & 3) == 3) {                                                            \
        int p_ = (t_) >> 2;                                                           \
        _Pragma("unroll") for (int j = 0; j < 4; ++j) {                               \
            sc[(0 * 16 + (lane & 15)) * 17 + ((lane >> 4) << 2) + j] = acc0[j];       \
            sc[(1 * 16 + (lane & 15)) * 17 + ((lane >> 4) << 2) + j] = acc1[j];       \
        }                                                                             \
        asm volatile("s_waitcnt lgkmcnt(0)" ::: "memory");                            \
        __builtin_amdgcn_sched_barrier(0);                                            \
        int b_ = lane >> 1, p2_ = lane & 1;                                           \
        int midx0 = (int)mb0 + p_ * 16;                                               \
        _Pragma("unroll") for (int j = 0; j < 8; ++j) {                               \
            int m_ = ((b_ + j) & 7) + p2_ * 8;                                        \
            float v_ = sc[b_ * 17 + m_];                                              \
            BUBBLE8(v_, midx0 + m_, s8, i8);                                          \
        }                                                                             \
        asm volatile("s_waitcnt lgkmcnt(0)" ::: "memory");                            \
        __builtin_amdgcn_sched_barrier(0);                                            \
        acc0 = (f32x4){0.f, 0.f, 0.f, 0.f};                                           \
        acc1 = (f32x4){0.f, 0.f, 0.f, 0.f};                                           \
    } }

    f32x4 acc0 = (f32x4){0.f, 0.f, 0.f, 0.f};
    f32x4 acc1 = (f32x4){0.f, 0.f, 0.f, 0.f};
    s16x8 qfA[16], qfB[16];

    // prologue: [tile0:16][qfA(0):16][tile1:16]
    TISSUE(0);
    __builtin_amdgcn_sched_barrier(0);
    QLOAD(qfA, 0);
    __builtin_amdgcn_sched_barrier(0);
    TISSUE(1);
    __builtin_amdgcn_sched_barrier(0);

    for (int t = 0; t < NCHUNK; t += 2) {
        // even chunk t (uses qfA). outstanding: [T t][qfA t][T t+1]
        asm volatile("s_waitcnt vmcnt(16)" ::: "memory");
        __builtin_amdgcn_sched_barrier(0);
        QLOAD(qfB, t + 1);                    // qf for odd chunk
        __builtin_amdgcn_sched_barrier(0);
        if (t + 2 < NCHUNK) TISSUE(t + 2);
        __builtin_amdgcn_sched_barrier(0);
        COMPUTE(t, qfA);

        // odd chunk t+1 (uses qfB). outstanding: [T t+1][qfB][T t+2?]
        if (t + 2 < NCHUNK) {
            asm volatile("s_waitcnt vmcnt(16)" ::: "memory");
        } else {
            asm volatile("s_waitcnt vmcnt(0)" ::: "memory");
        }
        __builtin_amdgcn_sched_barrier(0);
        if (t + 2 < NCHUNK) QLOAD(qfA, t + 2);
        __builtin_amdgcn_sched_barrier(0);
        if (t + 3 < NCHUNK) TISSUE(t + 3);
        __builtin_amdgcn_sched_barrier(0);
        COMPUTE(t + 1, qfB);
    }
#undef TISSUE
#undef QLOAD
#undef COMPUTE

    // merge lane pair (b = lane>>1 identical for the pair), lane&1==0 writes
    {
        float ov[8]; int oi[8];
#pragma unroll
        for (int u = 0; u < 8; ++u) { ov[u] = s8[u]; oi[u] = i8[u]; }
#pragma unroll
        for (int u = 0; u < 8; ++u) {
            float pv = __shfl_xor(ov[u], 1);
            int pi = __shfl_xor(oi[u], 1);
            BUBBLE8(pv, pi, s8, i8);
        }
        if ((lane & 1) == 0) {
            int b = lane >> 1;
#pragma unroll
            for (int u = 0; u < 8; ++u) {
                candS[(size_t)b * (NSB * 8) + blockIdx.x * 8 + u] = s8[u] * 0.03125f;
                candI[(size_t)b * (NSB * 8) + blockIdx.x * 8 + u] = i8[u];
            }
        }
    }
}

// Per b: merge 4096 approx candidates -> 64 survivors -> EXACT f32 rescore ->
// exact top-8 + softmax + weighted gather.
__global__ __launch_bounds__(256) void finalize_k(const float* __restrict__ candS,
                                                  const int* __restrict__ candI,
                                                  const float* __restrict__ memb,
                                                  const float* __restrict__ q,
                                                  float* __restrict__ out) {
    __shared__ float cs[256 * 9];
    __shared__ int ci[256 * 9];
    __shared__ float csA[64 * 9];
    __shared__ int ciA[64 * 9];
    __shared__ float exsc[64];
    __shared__ int exid[64];
    __shared__ float wgt[8];
    __shared__ int widx[8];
    int b = blockIdx.x, tid = threadIdx.x;
    const float* S = candS + (size_t)b * (NSB * 8);
    const int* I = candI + (size_t)b * (NSB * 8);

    {   // A: 256 threads x 16 candidates
        float s[8]; int si[8];
#pragma unroll
        for (int u = 0; u < 8; ++u) { s[u] = -INFINITY; si[u] = -1; }
        for (int j = 0; j < 16; ++j)
            BUBBLE8(S[tid * 16 + j], I[tid * 16 + j], s, si);
#pragma unroll
        for (int u = 0; u < 8; ++u) { cs[tid * 9 + u] = s[u]; ci[tid * 9 + u] = si[u]; }
    }
    __syncthreads();
    if (tid < 64) {   // B: merge 4 lists
        float s[8]; int si[8];
#pragma unroll
        for (int u = 0; u < 8; ++u) { s[u] = -INFINITY; si[u] = -1; }
        for (int tt = 0; tt < 4; ++tt)
#pragma unroll
            for (int u = 0; u < 8; ++u)
                BUBBLE8(cs[(tid * 4 + tt) * 9 + u], ci[(tid * 4 + tt) * 9 + u], s, si);
#pragma unroll
        for (int u = 0; u < 8; ++u) { csA[tid * 9 + u] = s[u]; ciA[tid * 9 + u] = si[u]; }
    }
    __syncthreads();
    if (tid < 8) {    // C: merge 8 lists -> 64 survivors (superset of true top-8)
        float s[8]; int si[8];
#pragma unroll
        for (int u = 0; u < 8; ++u) { s[u] = -INFINITY; si[u] = -1; }
        for (int tt = 0; tt < 8; ++tt)
#pragma unroll
            for (int u = 0; u < 8; ++u)
                BUBBLE8(csA[(tid * 8 + tt) * 9 + u], ciA[(tid * 8 + tt) * 9 + u], s, si);
#pragma unroll
        for (int u = 0; u < 8; ++u) exid[tid * 8 + u] = si[u];
    }
    __syncthreads();
    {   // D: exact f32 rescore; wave w -> candidates w*16..+15
        int w = tid >> 6, lane = tid & 63;
        const float4* qr = (const float4*)(q + (size_t)b * NC);
        for (int i = 0; i < 16; ++i) {
            int c = w * 16 + i;
            int row = exid[c];
            const float4* mr = (const float4*)(memb + (size_t)row * NC);
            float d = 0.f;
#pragma unroll
            for (int e = 0; e < 4; ++e) {
                float4 m4 = mr[e * 64 + lane];
                float4 q4 = qr[e * 64 + lane];
                d += m4.x * q4.x + m4.y * q4.y + m4.z * q4.z + m4.w * q4.w;
            }
#pragma unroll
            for (int off = 32; off; off >>= 1) d += __shfl_xor(d, off);
            if (lane == 0) exsc[c] = d * 0.03125f;
        }
    }
    __syncthreads();
    if (tid == 0) {   // E: exact top-8 of 64 + softmax
        float s4[8]; int si4[8];
#pragma unroll
        for (int u = 0; u < 8; ++u) { s4[u] = -INFINITY; si4[u] = -1; }
        for (int j = 0; j < 64; ++j)
            BUBBLE8(exsc[j], exid[j], s4, si4);
        float m = s4[0], sum = 0.f, w[8];
#pragma unroll
        for (int u = 0; u < 8; ++u) { w[u] = __expf(s4[u] - m); sum += w[u]; }
        float inv = 1.0f / sum;
#pragma unroll
        for (int u = 0; u < 8; ++u) { wgt[u] = w[u] * inv; widx[u] = si4[u]; }
    }
    __syncthreads();
    {   // F: weighted gather
        float wv[8]; int ix[8];
#pragma unroll
        for (int u = 0; u < 8; ++u) { wv[u] = wgt[u]; ix[u] = widx[u]; }
        float4 o = make_float4(0.f, 0.f, 0.f, 0.f);
#pragma unroll
        for (int u = 0; u < 8; ++u) {
            float4 r = ((const float4*)(memb + (size_t)ix[u] * NC))[tid];
            o.x = fmaf(wv[u], r.x, o.x);
            o.y = fmaf(wv[u], r.y, o.y);
            o.z = fmaf(wv[u], r.z, o.z);
            o.w = fmaf(wv[u], r.w, o.w);
        }
        ((float4*)(out + (size_t)b * NC))[tid] = o;
    }
}

extern "C" void kernel_launch(void* const* d_in, const int* in_sizes, int n_in,
                              void* d_out, int out_size, void* d_ws, size_t ws_size,
                              hipStream_t stream) {
    const float* seg  = (const float*)d_in[0];
    const float* Wq   = (const float*)d_in[1];
    const float* bq   = (const float*)d_in[2];
    const float* memb = (const float*)d_in[3];
    float* ws = (float*)d_ws;
    float* part  = ws + OFF_PART;
    float* mean  = ws + OFF_MEAN;
    float* q     = ws + OFF_Q;
    s16x8* qb    = (s16x8*)(ws + OFF_QB);
    float* candS = ws + OFF_CS;           // overlays part (safe: part dead by then)
    int*   candI = (int*)(ws + OFF_CI);
    float* out = (float*)d_out;

    mean_partial_k<<<NB * 32, 256, 0, stream>>>(seg, part);
    mean_finalize_k<<<(NB * NC) / 256, 256, 0, stream>>>(part, mean);
    qproj_k<<<512, 256, 0, stream>>>(mean, Wq, bq, q);
    qbf_k<<<16, 256, 0, stream>>>(q, qb);
    scores_mfma_k<<<NSB, 64, 0, stream>>>(memb, qb, candS, candI);
    finalize_k<<<NB, 256, 0, stream>>>(candS, candI, memb, q, out);
}

// Round 15
// 204.605 us; speedup vs baseline: 4.0924x; 1.0210x over previous
//
#include <hip/hip_runtime.h>
#include <hip/hip_bf16.h>
#include <math.h>

#define NB 32
#define NT 2048
#define NC 1024
#define NM 131072
#define TOPK 8
#define NSB 256             // scores grid (1 block/CU)
#define ROWS_PB 512         // rows per block
#define NP 32               // panels per block (16 rows each)
#define SLOTF 260           // LDS slot stride (floats): 1 KB data + 16 B pad
#define TILEF (4 * 16 * SLOTF)       // one panel buffer: 16,640 floats
#define SCOFF (2 * TILEF)            // sc base: 33,280
#define SMEMF (SCOFF + 2 * 32 * 17)  // 34,368 floats = 137,472 B

typedef __attribute__((ext_vector_type(8))) short s16x8;   // 8 bf16 = 16 B
typedef __attribute__((ext_vector_type(4))) float f32x4;   // MFMA acc
typedef __attribute__((ext_vector_type(4))) int i32x4;

// ws layout (float offsets). candS/candI OVERLAY part (part dead after mean_finalize_k).
#define OFF_PART 0
#define OFF_CS   0                   // 32*256*8 = 65536 floats
#define OFF_CI   65536               // ends 131072 < part's 1048576
#define OFF_MEAN 1048576
#define OFF_Q    (OFF_MEAN + 32768)
#define OFF_QB   (OFF_Q + 32768)     // 4096 s16x8 = 64 KB

__device__ __forceinline__ unsigned short f2bf(float f) {
    unsigned u = __float_as_uint(f);
    unsigned r = (u + 0x7FFFu + ((u >> 16) & 1u)) >> 16;
    return (unsigned short)r;
}

__device__ __forceinline__ void gl_lds16(const float* g, float* l) {
    // one instruction: 64 lanes x 16B -> LDS base + lane*16 (contiguous 1 KB)
    __builtin_amdgcn_global_load_lds((const __attribute__((address_space(1))) void*)g,
                                     (__attribute__((address_space(3))) void*)l, 16, 0, 0);
}

__global__ __launch_bounds__(256) void mean_partial_k(const float* __restrict__ seg,
                                                      float* __restrict__ part) {
    int blk = blockIdx.x;            // 1024 = 32 b * 32 tc
    int b = blk >> 5, tc = blk & 31;
    int tid = threadIdx.x;
    const float4* src = (const float4*)(seg + ((size_t)b * NT + (size_t)tc * 64) * NC);
    float4 acc = make_float4(0.f, 0.f, 0.f, 0.f);
#pragma unroll 4
    for (int t = 0; t < 64; ++t) {
        float4 v = src[(size_t)t * 256 + tid];
        acc.x += v.x; acc.y += v.y; acc.z += v.z; acc.w += v.w;
    }
    ((float4*)(part + ((size_t)b * 32 + tc) * NC))[tid] = acc;
}

__global__ __launch_bounds__(256) void mean_finalize_k(const float* __restrict__ part,
                                                       float* __restrict__ mean) {
    int i = blockIdx.x * 256 + threadIdx.x;   // 32768
    int b = i >> 10, c = i & 1023;
    float s = 0.f;
#pragma unroll
    for (int tc = 0; tc < 32; ++tc) s += part[((size_t)b * 32 + tc) * NC + c];
    mean[i] = s * (1.0f / NT);
}

__global__ __launch_bounds__(256) void qproj_k(const float* __restrict__ mean,
                                               const float* __restrict__ Wq,
                                               const float* __restrict__ bq,
                                               float* __restrict__ q) {
    int wave = (blockIdx.x * 256 + threadIdx.x) >> 6;   // 2048 waves
    int lane = threadIdx.x & 63;
    int o0 = wave * 16;
    for (int j = 0; j < 16; ++j) {
        int o = o0 + j;                 // < 32768
        int b = o >> 10, i = o & 1023;
        const float4* wr = (const float4*)(Wq + (size_t)i * NC);
        const float4* mr = (const float4*)(mean + (size_t)b * NC);
        float acc = 0.f;
#pragma unroll
        for (int e = 0; e < 4; ++e) {
            float4 w4 = wr[lane * 4 + e];
            float4 m4 = mr[lane * 4 + e];
            acc += w4.x * m4.x + w4.y * m4.y + w4.z * m4.z + w4.w * m4.w;
        }
#pragma unroll
        for (int off = 32; off; off >>= 1) acc += __shfl_xor(acc, off);
        if (lane == 0) q[o] = acc + bq[i];
    }
}

// qb[(ksg*2+n)*64 + lane][e] = bf16(q[n*16+(lane&15)][ksg*32+(lane>>4)*8+e])
__global__ __launch_bounds__(256) void qbf_k(const float* __restrict__ q,
                                             s16x8* __restrict__ qb) {
    int idx = blockIdx.x * 256 + threadIdx.x;   // 4096
    int lane = idx & 63, n = (idx >> 6) & 1, ks = idx >> 7;
    int b = n * 16 + (lane & 15);
    int k0 = ks * 32 + ((lane >> 4) << 3);
    s16x8 v;
#pragma unroll
    for (int e = 0; e < 8; ++e) v[e] = (short)f2bf(q[(size_t)b * NC + k0 + e]);
    qb[idx] = v;
}

#define BUBBLE8(v, vi, s, si)                                   \
    {                                                           \
        float _v = (v); int _vi = (vi);                         \
        _Pragma("unroll")                                       \
        for (int _u = 0; _u < 8; ++_u) {                        \
            bool _gt = _v > s[_u];                               \
            float _ts = _gt ? _v : s[_u];                       \
            int _ti = _gt ? _vi : si[_u];                       \
            _v = _gt ? s[_u] : _v;                              \
            _vi = _gt ? si[_u] : _vi;                           \
            s[_u] = _ts; si[_u] = _ti;                          \
        }                                                       \
    }

#define BUBBLE8F(v, s)                                          \
    {                                                           \
        float _v = (v);                                         \
        _Pragma("unroll")                                       \
        for (int _u = 0; _u < 8; ++_u) {                        \
            bool _gt = _v > s[_u];                               \
            float _ts = _gt ? _v : s[_u];                       \
            _v = _gt ? s[_u] : _v;                              \
            s[_u] = _ts;                                        \
        }                                                       \
    }

// Sequential-panel MFMA scores. grid 256 (1 block/CU), 4 waves = (b-tile n x
// k-half kh). Block owns 512 consecutive rows = 2 MB, fetched as one purely
// sequential stream of 16-row panels (64 KB) via 16 gl_lds16 per panel, 16-B
// padded [c][r] slots (row-step 1 mod 8 bank-quads -> 2-way, free). Double
// buffer + counted vmcnt(16): panel p+1 always in flight. qf fragments are
// PANEL-INVARIANT per wave (fixed k-half) -> loaded once, 64 VGPR. Per panel:
// 16 MFMA/wave, cross-wave k-sum via sc, 9-bit local-index mantissa-embed
// top-8 scan. Compute ~1000 cyc << 6400-cyc fetch budget -> fetch-bound.
__global__ __launch_bounds__(256, 1) void scores_mfma_k(const float* __restrict__ memb,
                                                        const s16x8* __restrict__ qb,
                                                        float* __restrict__ candS,
                                                        int* __restrict__ candI) {
    extern __shared__ __align__(16) float smemf[];   // SMEMF floats (137,472 B)
    int tid = threadIdx.x, lane = tid & 63, ws = tid >> 6;
    int n = ws & 1, kh = ws >> 1;
    size_t mb0 = (size_t)blockIdx.x * ROWS_PB;

    float s8[8];
#pragma unroll
    for (int u = 0; u < 8; ++u) s8[u] = -INFINITY;

#define TISSUE(p_) { float* lb = smemf + ((p_) & 1) * TILEF;                          \
    const float* gb = memb + (mb0 + (size_t)(p_) * 16) * NC + lane * 4;               \
    _Pragma("unroll") for (int i_ = 0; i_ < 16; ++i_) {                               \
        int r_ = ws * 4 + (i_ >> 2), c_ = i_ & 3;                                     \
        gl_lds16(gb + (size_t)r_ * NC + c_ * 256, lb + (c_ * 16 + r_) * SLOTF); } }

    // qf: fixed per wave (its k-half, its b-tile) — loaded once
    s16x8 qf[16];
#pragma unroll
    for (int s = 0; s < 16; ++s)
        qf[s] = qb[((kh * 16 + s) * 2 + n) * 64 + lane];

    TISSUE(0);
    TISSUE(1);

    for (int p = 0; p < NP; ++p) {
        if (p + 1 < NP) { asm volatile("s_waitcnt vmcnt(16)" ::: "memory"); }
        else            { asm volatile("s_waitcnt vmcnt(0)" ::: "memory"); }
        __builtin_amdgcn_sched_barrier(0);
        __builtin_amdgcn_s_barrier();         // panel p visible to all waves
        __builtin_amdgcn_sched_barrier(0);

        // compute panel p: 16 ks steps of this wave's k-half
        f32x4 acc = (f32x4){0.f, 0.f, 0.f, 0.f};
        const float* tb = smemf + (p & 1) * TILEF;
#pragma unroll
        for (int s = 0; s < 16; ++s) {
            int ksg = kh * 16 + s;
            const float* ap = tb + ((ksg >> 3) * 16 + (lane & 15)) * SLOTF
                            + (ksg & 7) * 32 + ((lane >> 4) << 3);
            uint4 lo = *(const uint4*)(ap);
            uint4 hi = *(const uint4*)(ap + 4);
            i32x4 ai;
            ai[0] = __builtin_amdgcn_perm(lo.y, lo.x, 0x07060302u);
            ai[1] = __builtin_amdgcn_perm(lo.w, lo.z, 0x07060302u);
            ai[2] = __builtin_amdgcn_perm(hi.y, hi.x, 0x07060302u);
            ai[3] = __builtin_amdgcn_perm(hi.w, hi.z, 0x07060302u);
            s16x8 a = __builtin_bit_cast(s16x8, ai);
            acc = __builtin_amdgcn_mfma_f32_16x16x32_bf16(a, qf[s], acc, 0, 0, 0);
        }

        // partials -> sc[kh][b][m] (D layout m89: col=lane&15 -> b, row=(lane>>4)*4+j -> m)
        {
            int bcol = n * 16 + (lane & 15);
            int mrow = (lane >> 4) << 2;
#pragma unroll
            for (int j = 0; j < 4; ++j)
                smemf[SCOFF + (kh * 32 + bcol) * 17 + mrow + j] = acc[j];
        }
        asm volatile("s_waitcnt lgkmcnt(0)" ::: "memory");
        __builtin_amdgcn_sched_barrier(0);
        __builtin_amdgcn_s_barrier();
        __builtin_amdgcn_sched_barrier(0);

        // scan: thread owns (b=tid>>3, pq=tid&7), rows {pq, pq+8}; sum 2 k-halves;
        // embed 9-bit local idx (p*16+m) in low mantissa bits
        {
            int b = tid >> 3, pq = tid & 7;
#pragma unroll
            for (int rr = 0; rr < 2; ++rr) {
                int m = pq + rr * 8;
                float v = smemf[SCOFF + b * 17 + m]
                        + smemf[SCOFF + (32 + b) * 17 + m];
                unsigned uu = (__float_as_uint(v) & ~0x1FFu) | (unsigned)(p * 16 + m);
                BUBBLE8F(__uint_as_float(uu), s8);
            }
        }
        __builtin_amdgcn_sched_barrier(0);
        __builtin_amdgcn_s_barrier();         // sc reads + tile reads done; bufs free
        __builtin_amdgcn_sched_barrier(0);

        if (p + 2 < NP) TISSUE(p + 2);
    }
#undef TISSUE

    // block-level merge: 256 per-thread lists -> per-b top-8 (float-only tree)
    {
        float* cs = smemf;                    // [256][9]
#pragma unroll
        for (int u = 0; u < 8; ++u) cs[tid * 9 + u] = s8[u];
        __syncthreads();
        float* csA = smemf + 2304;            // [64][9]
        if (tid < 64) {
            float s2[8];
#pragma unroll
            for (int u = 0; u < 8; ++u) s2[u] = -INFINITY;
            int t0 = (tid >> 1) * 8 + (tid & 1) * 4;
            for (int tt = 0; tt < 4; ++tt)
#pragma unroll
                for (int u = 0; u < 8; ++u)
                    BUBBLE8F(cs[(t0 + tt) * 9 + u], s2);
#pragma unroll
            for (int u = 0; u < 8; ++u) csA[tid * 9 + u] = s2[u];
        }
        __syncthreads();
        if (tid < 32) {
            float s3[8];
#pragma unroll
            for (int u = 0; u < 8; ++u) s3[u] = -INFINITY;
            for (int j = 0; j < 16; ++j)
                BUBBLE8F(csA[(tid * 2 + (j >> 3)) * 9 + (j & 7)], s3);
#pragma unroll
            for (int u = 0; u < 8; ++u) {
                candS[((size_t)tid * NSB + blockIdx.x) * 8 + u] = s3[u] * 0.03125f;
                candI[((size_t)tid * NSB + blockIdx.x) * 8 + u] =
                    (int)mb0 + (int)(__float_as_uint(s3[u]) & 0x1FFu);
            }
        }
    }
}

// Per b: merge 2048 approx candidates -> 64 survivors -> EXACT f32 rescore ->
// exact top-8 + softmax + weighted gather.
__global__ __launch_bounds__(256) void finalize_k(const float* __restrict__ candS,
                                                  const int* __restrict__ candI,
                                                  const float* __restrict__ memb,
                                                  const float* __restrict__ q,
                                                  float* __restrict__ out) {
    __shared__ float cs[256 * 9];
    __shared__ int ci[256 * 9];
    __shared__ float csA[64 * 9];
    __shared__ int ciA[64 * 9];
    __shared__ float exsc[64];
    __shared__ int exid[64];
    __shared__ float wgt[8];
    __shared__ int widx[8];
    int b = blockIdx.x, tid = threadIdx.x;
    const float* S = candS + (size_t)b * (NSB * 8);
    const int* I = candI + (size_t)b * (NSB * 8);

    {   // A: 256 threads x 8 candidates
        float s[8]; int si[8];
#pragma unroll
        for (int u = 0; u < 8; ++u) { s[u] = -INFINITY; si[u] = -1; }
        for (int j = 0; j < 8; ++j)
            BUBBLE8(S[tid * 8 + j], I[tid * 8 + j], s, si);
#pragma unroll
        for (int u = 0; u < 8; ++u) { cs[tid * 9 + u] = s[u]; ci[tid * 9 + u] = si[u]; }
    }
    __syncthreads();
    if (tid < 64) {   // B: merge 4 lists
        float s[8]; int si[8];
#pragma unroll
        for (int u = 0; u < 8; ++u) { s[u] = -INFINITY; si[u] = -1; }
        for (int tt = 0; tt < 4; ++tt)
#pragma unroll
            for (int u = 0; u < 8; ++u)
                BUBBLE8(cs[(tid * 4 + tt) * 9 + u], ci[(tid * 4 + tt) * 9 + u], s, si);
#pragma unroll
        for (int u = 0; u < 8; ++u) { csA[tid * 9 + u] = s[u]; ciA[tid * 9 + u] = si[u]; }
    }
    __syncthreads();
    if (tid < 8) {    // C: merge 8 lists -> 64 survivors (superset of true top-8)
        float s[8]; int si[8];
#pragma unroll
        for (int u = 0; u < 8; ++u) { s[u] = -INFINITY; si[u] = -1; }
        for (int tt = 0; tt < 8; ++tt)
#pragma unroll
            for (int u = 0; u < 8; ++u)
                BUBBLE8(csA[(tid * 8 + tt) * 9 + u], ciA[(tid * 8 + tt) * 9 + u], s, si);
#pragma unroll
        for (int u = 0; u < 8; ++u) exid[tid * 8 + u] = si[u];
    }
    __syncthreads();
    {   // D: exact f32 rescore; wave w -> candidates w*16..+15
        int w = tid >> 6, lane = tid & 63;
        const float4* qr = (const float4*)(q + (size_t)b * NC);
        for (int i = 0; i < 16; ++i) {
            int c = w * 16 + i;
            int row = exid[c];
            const float4* mr = (const float4*)(memb + (size_t)row * NC);
            float d = 0.f;
#pragma unroll
            for (int e = 0; e < 4; ++e) {
                float4 m4 = mr[e * 64 + lane];
                float4 q4 = qr[e * 64 + lane];
                d += m4.x * q4.x + m4.y * q4.y + m4.z * q4.z + m4.w * q4.w;
            }
#pragma unroll
            for (int off = 32; off; off >>= 1) d += __shfl_xor(d, off);
            if (lane == 0) exsc[c] = d * 0.03125f;
        }
    }
    __syncthreads();
    if (tid == 0) {   // E: exact top-8 of 64 + softmax
        float s4[8]; int si4[8];
#pragma unroll
        for (int u = 0; u < 8; ++u) { s4[u] = -INFINITY; si4[u] = -1; }
        for (int j = 0; j < 64; ++j)
            BUBBLE8(exsc[j], exid[j], s4, si4);
        float m = s4[0], sum = 0.f, w[8];
#pragma unroll
        for (int u = 0; u < 8; ++u) { w[u] = __expf(s4[u] - m); sum += w[u]; }
        float inv = 1.0f / sum;
#pragma unroll
        for (int u = 0; u < 8; ++u) { wgt[u] = w[u] * inv; widx[u] = si4[u]; }
    }
    __syncthreads();
    {   // F: weighted gather
        float wv[8]; int ix[8];
#pragma unroll
        for (int u = 0; u < 8; ++u) { wv[u] = wgt[u]; ix[u] = widx[u]; }
        float4 o = make_float4(0.f, 0.f, 0.f, 0.f);
#pragma unroll
        for (int u = 0; u < 8; ++u) {
            float4 r = ((const float4*)(memb + (size_t)ix[u] * NC))[tid];
            o.x = fmaf(wv[u], r.x, o.x);
            o.y = fmaf(wv[u], r.y, o.y);
            o.z = fmaf(wv[u], r.z, o.z);
            o.w = fmaf(wv[u], r.w, o.w);
        }
        ((float4*)(out + (size_t)b * NC))[tid] = o;
    }
}

extern "C" void kernel_launch(void* const* d_in, const int* in_sizes, int n_in,
                              void* d_out, int out_size, void* d_ws, size_t ws_size,
                              hipStream_t stream) {
    const float* seg  = (const float*)d_in[0];
    const float* Wq   = (const float*)d_in[1];
    const float* bq   = (const float*)d_in[2];
    const float* memb = (const float*)d_in[3];
    float* ws = (float*)d_ws;
    float* part  = ws + OFF_PART;
    float* mean  = ws + OFF_MEAN;
    float* q     = ws + OFF_Q;
    s16x8* qb    = (s16x8*)(ws + OFF_QB);
    float* candS = ws + OFF_CS;           // overlays part (safe: part dead by then)
    int*   candI = (int*)(ws + OFF_CI);
    float* out = (float*)d_out;

    (void)hipFuncSetAttribute((const void*)scores_mfma_k,
                              hipFuncAttributeMaxDynamicSharedMemorySize,
                              SMEMF * 4);

    mean_partial_k<<<NB * 32, 256, 0, stream>>>(seg, part);
    mean_finalize_k<<<(NB * NC) / 256, 256, 0, stream>>>(part, mean);
    qproj_k<<<512, 256, 0, stream>>>(mean, Wq, bq, q);
    qbf_k<<<16, 256, 0, stream>>>(q, qb);
    scores_mfma_k<<<NSB, 256, SMEMF * 4, stream>>>(memb, qb, candS, candI);
    finalize_k<<<NB, 256, 0, stream>>>(candS, candI, memb, q, out);
}